// Round 8
// baseline (345.641 us; speedup 1.0000x reference)
//
#include <hip/hip_runtime.h>

#define CH 128
#define NB 64
#define LPAD 4
#define LSTR (NB + LPAD)
#define FB_NB 16
#define SC_T 256
#define SC_I 8
#define CSH 9
#define CSZ 512            // nodes per coarse bucket
#define NBMAX 512          // max coarse buckets (n_nodes <= 262144)
#define A1_T 1024
#define A1_E 8             // edges per thread in bin_kernel

typedef __attribute__((ext_vector_type(8))) __bf16 bf16x8;
typedef __attribute__((ext_vector_type(4))) float f32x4;

// ---------------------------------------------------------------------------
// bf16 helpers (RNE)
// ---------------------------------------------------------------------------
__device__ __forceinline__ unsigned bf16rne(float f) {
    unsigned u = __float_as_uint(f);
    return (u + 0x7FFFu + ((u >> 16) & 1u)) >> 16;
}
__device__ __forceinline__ unsigned pack2bf(float lo, float hi) {
    return bf16rne(lo) | (bf16rne(hi) << 16);
}

// int64-vs-int32 edge_index detection (odd words all zero => int64 < 2^31)
__device__ __forceinline__ int detect_f(const void* edges) {
    const int* ei = (const int*)edges;
    int hi_zero = (ei[1] == 0) & (ei[3] == 0) & (ei[5] == 0) & (ei[7] == 0);
    int lo_any  = (ei[0] | ei[2] | ei[4] | ei[6]) != 0;
    return hi_zero & lo_any;
}
__device__ __forceinline__ int load_dst(const void* edges, int e, int n_edges, int f) {
    const int* p = (const int*)edges;
    return f ? p[2 * (e + n_edges)] : p[e + n_edges];
}
__device__ __forceinline__ int load_src(const void* edges, int e, int f) {
    const int* p = (const int*)edges;
    return f ? p[2 * e] : p[e];
}

// ---------------------------------------------------------------------------
// prep2: coarse-bucket histogram (LDS, 512 bins) + x -> bf16 cast
// ---------------------------------------------------------------------------
__global__ __launch_bounds__(256) void prep2_kernel(
    const void* __restrict__ edges, int* __restrict__ btot, int n_edges,
    const float* __restrict__ x, ushort* __restrict__ xb, long long n_x,
    int nbins, int hist_blocks)
{
    __shared__ int lh[NBMAX];
    const int blk = blockIdx.x, tid = threadIdx.x;
    if (blk < hist_blocks) {
        for (int i = tid; i < nbins; i += 256) lh[i] = 0;
        __syncthreads();
        const int f  = detect_f(edges);
        const int e0 = blk * (256 * A1_E) + tid;
#pragma unroll
        for (int j = 0; j < A1_E; ++j) {
            int e = e0 + j * 256;
            if (e < n_edges) atomicAdd(&lh[load_dst(edges, e, n_edges, f) >> CSH], 1);
        }
        __syncthreads();
        for (int i = tid; i < nbins; i += 256)
            if (lh[i]) atomicAdd(&btot[i], lh[i]);
    }
    long long i = (long long)blk * 256 + tid;
    long long base = i * 8;
    if (base + 8 <= n_x) {
        float4 a = *(const float4*)(x + base);
        float4 c = *(const float4*)(x + base + 4);
        uint4 o;
        o.x = pack2bf(a.x, a.y);
        o.y = pack2bf(a.z, a.w);
        o.z = pack2bf(c.x, c.y);
        o.w = pack2bf(c.z, c.w);
        *(uint4*)(xb + base) = o;
    } else {
        for (long long j = base; j < n_x; ++j) xb[j] = (ushort)bf16rne(x[j]);
    }
}

// W transpose+cast: Wt[j][k] (j=out ch, k=0..255; k<128 -> Wl, else Wr), bf16
__global__ __launch_bounds__(256) void wt_kernel(
    const float* __restrict__ Wl, const float* __restrict__ Wr,
    ushort* __restrict__ Wt)
{
    int idx = blockIdx.x * 256 + threadIdx.x;
    if (idx >= CH * 2 * CH) return;
    int j = idx >> 8, k = idx & 255;
    float v = (k < CH) ? Wl[k * CH + j] : Wr[(k - CH) * CH + j];
    Wt[idx] = (ushort)bf16rne(v);
}

// ---------------------------------------------------------------------------
// 1-block scan of bucket totals -> bbase / gcursor; sentinels.
// ---------------------------------------------------------------------------
__global__ __launch_bounds__(NBMAX) void scanb_kernel(
    const int* __restrict__ btot, int* __restrict__ bbase,
    int* __restrict__ gcursor, int* __restrict__ offs,
    int nbins, int n_edges, int n_nodes)
{
    __shared__ int s[NBMAX];
    const int t = threadIdx.x;
    int v = (t < nbins) ? btot[t] : 0;
    s[t] = v;
    __syncthreads();
    for (int off = 1; off < NBMAX; off <<= 1) {
        int val = (t >= off) ? s[t - off] : 0;
        __syncthreads();
        s[t] += val;
        __syncthreads();
    }
    int excl = s[t] - v;
    if (t < nbins) { bbase[t] = excl; gcursor[t] = excl; }
    if (t == 0) { bbase[nbins] = n_edges; offs[n_nodes] = n_edges; }
}

// ---------------------------------------------------------------------------
// bin edges into coarse buckets with LDS histogram + run reservation.
// entry = src | (dst & 511) << 22   (requires n_nodes < 2^22)
// ---------------------------------------------------------------------------
__global__ __launch_bounds__(A1_T) void bin_kernel(
    const void* __restrict__ edges, int* __restrict__ gcursor,
    unsigned* __restrict__ binned, int n_edges, int nbins)
{
    __shared__ int lcnt[NBMAX];
    __shared__ int lbase[NBMAX];
    const int f   = detect_f(edges);
    const int tid = threadIdx.x;
    for (int i = tid; i < nbins; i += A1_T) lcnt[i] = 0;
    __syncthreads();

    int bin[A1_E], lrank[A1_E];
    unsigned ent[A1_E];
    const int e0 = blockIdx.x * (A1_T * A1_E);
#pragma unroll
    for (int j = 0; j < A1_E; ++j) {
        int e = e0 + j * A1_T + tid;
        bin[j] = -1;
        if (e < n_edges) {
            int s = load_src(edges, e, f);
            int d = load_dst(edges, e, n_edges, f);
            bin[j]   = d >> CSH;
            ent[j]   = (unsigned)s | ((unsigned)(d & (CSZ - 1)) << 22);
            lrank[j] = atomicAdd(&lcnt[bin[j]], 1);
        }
    }
    __syncthreads();
    for (int i = tid; i < nbins; i += A1_T)
        lbase[i] = atomicAdd(&gcursor[i], lcnt[i]);
    __syncthreads();
#pragma unroll
    for (int j = 0; j < A1_E; ++j)
        if (bin[j] >= 0) binned[lbase[bin[j]] + lrank[j]] = ent[j];
}

// ---------------------------------------------------------------------------
// per-bucket: LDS count -> LDS scan -> write offs -> place into sorted.
// All writes in the block-exclusive window [bbase[c], bbase[c+1]).
// ---------------------------------------------------------------------------
__global__ __launch_bounds__(CSZ) void sortfine2_kernel(
    const unsigned* __restrict__ binned, const int* __restrict__ bbase,
    int* __restrict__ offs, int* __restrict__ sorted, int n_nodes)
{
    __shared__ int cnt[CSZ];
    __shared__ int sc[CSZ];
    __shared__ int cur[CSZ];
    const int c   = blockIdx.x;
    const int tid = threadIdx.x;
    cnt[tid] = 0;
    __syncthreads();
    const int start = bbase[c];
    const int end   = bbase[c + 1];
    for (int i = start + tid; i < end; i += CSZ)
        atomicAdd(&cnt[(binned[i] >> 22) & (CSZ - 1)], 1);
    __syncthreads();
    int v = cnt[tid];
    sc[tid] = v;
    __syncthreads();
    for (int off = 1; off < CSZ; off <<= 1) {
        int val = (tid >= off) ? sc[tid - off] : 0;
        __syncthreads();
        sc[tid] += val;
        __syncthreads();
    }
    int gpos = start + sc[tid] - v;        // global start of this node's range
    int node = (c << CSH) + tid;
    if (node < n_nodes) offs[node] = gpos;
    cur[tid] = gpos;
    __syncthreads();
    for (int i = start + tid; i < end; i += CSZ) {
        unsigned ent = binned[i];
        int r = atomicAdd(&cur[(ent >> 22) & (CSZ - 1)], 1);
        sorted[r] = (int)(ent & 0x3FFFFFu);
    }
}

// ---------------------------------------------------------------------------
// persistent fused gather-mean + MFMA GEMM. LDS = s_m only (17.4 KB).
// x A-fragments for the second MFMA half read directly from global xb.
// deg derived from offs diffs (offs has sentinel at n_nodes).
// ---------------------------------------------------------------------------
__global__ __launch_bounds__(256, 6) void fused_mfma_kernel(
    const ushort* __restrict__ xb,
    const int* __restrict__ sorted,
    const int* __restrict__ offs,
    const ushort* __restrict__ Wt,
    const float* __restrict__ bias,
    float* __restrict__ out,
    int n_nodes, int nE, int ntiles)
{
    __shared__ ushort s_m[64][136];

    const int tid  = threadIdx.x;
    const int wave = tid >> 6;
    const int lane = tid & 63;
    const int rA   = lane & 15;
    const int gA   = lane >> 4;
    const int oc0  = wave * 32;
    const float b0 = bias[oc0 + rA];
    const float b1 = bias[oc0 + 16 + rA];

    for (int tile = blockIdx.x; tile < ntiles; tile += gridDim.x) {
        const int node0 = tile * NB;
        const int first = node0 + wave * 16;

        if (first < n_nodes) {
            const int nval = min(16, n_nodes - first);

            const int base0 = offs[first];
            const int e_end = offs[first + nval];
            const int Ew      = e_end - base0;
            const int nb_full = Ew >> 4;
            const int rem     = Ew & 15;

            int   nstored   = 0;
            int   cur_start = base0;
            int   cur_end   = offs[first + 1];
            float alo = 0.f, ahi = 0.f;

            int sv_cur = 0, sv_nxt = 0;
            if (Ew > 0) sv_cur = sorted[min(base0 + lane, nE - 1)];

            auto flushfn = [&](int ii) {
                while (ii == cur_end && nstored < nval) {
                    float sc = 1.0f / fmaxf((float)(cur_end - cur_start), 1.0f);
                    *(unsigned*)&s_m[wave * 16 + nstored][lane * 2] =
                        pack2bf(alo * sc, ahi * sc);
                    alo = 0.f; ahi = 0.f;
                    ++nstored;
                    if (nstored < nval) {
                        cur_start = cur_end;
                        cur_end   = offs[first + nstored + 1];
                    }
                }
            };
            auto issue = [&](unsigned (&U)[16], int bb) {
                if ((bb & 3) == 0) {
                    if (bb > 0) sv_cur = sv_nxt;
                    int c = (bb >> 2) + 1;
                    if (c * 64 < Ew) sv_nxt = sorted[min(base0 + c * 64 + lane, nE - 1)];
                }
                int q = (bb & 3) * 16;
#pragma unroll
                for (int t = 0; t < 16; ++t) {
                    int s = __builtin_amdgcn_readfirstlane(__shfl(sv_cur, q + t));
                    U[t] = *(const unsigned*)(xb + (size_t)s * CH + lane * 2);
                }
            };
            auto accum = [&](unsigned (&U)[16], int bb) {
                int i0 = base0 + bb * 16;
#pragma unroll
                for (int t = 0; t < 16; ++t) {
                    flushfn(i0 + t);
                    alo += __uint_as_float(U[t] << 16);
                    ahi += __uint_as_float(U[t] & 0xFFFF0000u);
                }
            };

            unsigned uA[16], uB[16];
            if (nb_full > 0) issue(uA, 0);
            int bI = 0;
            while (bI < nb_full) {
                if (bI + 1 < nb_full) issue(uB, bI + 1);
                accum(uA, bI);
                ++bI;
                if (bI >= nb_full) break;
                if (bI + 1 < nb_full) issue(uA, bI + 1);
                accum(uB, bI);
                ++bI;
            }

            if (rem > 0) {
                if (nb_full > 0 && (nb_full & 3) == 0) sv_cur = sv_nxt;
                int q = (nb_full & 3) * 16;
                for (int t = 0; t < rem; ++t) {
                    int i = base0 + nb_full * 16 + t;
                    int s = __builtin_amdgcn_readfirstlane(__shfl(sv_cur, q + t));
                    unsigned u = *(const unsigned*)(xb + (size_t)s * CH + lane * 2);
                    flushfn(i);
                    alo += __uint_as_float(u << 16);
                    ahi += __uint_as_float(u & 0xFFFF0000u);
                }
            }
            while (nstored < nval) {
                float sc = 1.0f / fmaxf((float)(cur_end - cur_start), 1.0f);
                *(unsigned*)&s_m[wave * 16 + nstored][lane * 2] =
                    pack2bf(alo * sc, ahi * sc);
                alo = 0.f; ahi = 0.f;
                ++nstored;
                if (nstored < nval) {
                    cur_start = cur_end;
                    cur_end   = offs[first + nstored + 1];
                }
            }
        }
        __syncthreads();

        f32x4 acc[4][2];
#pragma unroll
        for (int nt = 0; nt < 4; ++nt) {
            acc[nt][0] = (f32x4){0.f, 0.f, 0.f, 0.f};
            acc[nt][1] = (f32x4){0.f, 0.f, 0.f, 0.f};
        }

#pragma unroll
        for (int ks = 0; ks < 8; ++ks) {
            const int kk = (ks & 3) * 32 + gA * 8;
            const ushort* wrow = Wt + ks * 32 + gA * 8;
            bf16x8 bf0 = __builtin_bit_cast(bf16x8,
                *(const uint4*)(wrow + (oc0 + rA) * 256));
            bf16x8 bf1 = __builtin_bit_cast(bf16x8,
                *(const uint4*)(wrow + (oc0 + 16 + rA) * 256));
#pragma unroll
            for (int nt = 0; nt < 4; ++nt) {
                bf16x8 af;
                if (ks < 4) {
                    af = __builtin_bit_cast(bf16x8,
                        *(const uint4*)&s_m[nt * 16 + rA][kk]);
                } else {
                    int row = node0 + nt * 16 + rA;
                    row = (row < n_nodes) ? row : (n_nodes - 1);
                    af = __builtin_bit_cast(bf16x8,
                        *(const uint4*)(xb + (size_t)row * CH + kk));
                }
                acc[nt][0] = __builtin_amdgcn_mfma_f32_16x16x32_bf16(af, bf0, acc[nt][0], 0, 0, 0);
                acc[nt][1] = __builtin_amdgcn_mfma_f32_16x16x32_bf16(af, bf1, acc[nt][1], 0, 0, 0);
            }
        }

#pragma unroll
        for (int nt = 0; nt < 4; ++nt) {
            int nbase = node0 + nt * 16 + gA * 4;
#pragma unroll
            for (int r = 0; r < 4; ++r) {
                int node = nbase + r;
                if (node < n_nodes) {
                    out[(size_t)node * CH + oc0 + rA]      = fmaxf(acc[nt][0][r] + b0, 0.f);
                    out[(size_t)node * CH + oc0 + 16 + rA] = fmaxf(acc[nt][1][r] + b1, 0.f);
                }
            }
        }
        __syncthreads();
    }
}

// ---------------------------------------------------------------------------
// legacy helpers for fallback tiers
// ---------------------------------------------------------------------------
__global__ __launch_bounds__(256) void hist_kernel(
    const void* __restrict__ edges, int* __restrict__ deg, int n_edges)
{
    const int f = detect_f(edges);
    int e = blockIdx.x * 256 + threadIdx.x;
    if (e >= n_edges) return;
    atomicAdd(&deg[load_dst(edges, e, n_edges, f)], 1);
}

__global__ __launch_bounds__(SC_T) void scan_blocks(
    const int* __restrict__ deg, int* __restrict__ offs,
    int* __restrict__ bsums, int n)
{
    __shared__ int s_sum[SC_T];
    const int t = threadIdx.x;
    const int base = blockIdx.x * SC_T * SC_I + t * SC_I;
    int v[SC_I];
    int tsum = 0;
#pragma unroll
    for (int i = 0; i < SC_I; ++i) {
        int idx = base + i;
        v[i] = (idx < n) ? deg[idx] : 0;
        tsum += v[i];
    }
    s_sum[t] = tsum;
    __syncthreads();
    for (int off = 1; off < SC_T; off <<= 1) {
        int val = (t >= off) ? s_sum[t - off] : 0;
        __syncthreads();
        s_sum[t] += val;
        __syncthreads();
    }
    int run = s_sum[t] - tsum;
#pragma unroll
    for (int i = 0; i < SC_I; ++i) {
        int idx = base + i;
        if (idx < n) offs[idx] = run;
        run += v[i];
    }
    if (t == SC_T - 1) bsums[blockIdx.x] = s_sum[t];
}

__global__ __launch_bounds__(256) void fixup_kernel(
    int* __restrict__ offs, const int* __restrict__ bsums,
    int* __restrict__ cursor, int n)
{
    int i = blockIdx.x * 256 + threadIdx.x;
    if (i >= n) return;
    int bucket = i / (SC_T * SC_I);
    int add = 0;
    for (int j = 0; j < bucket; ++j) add += bsums[j];
    int o = offs[i] + add;
    offs[i] = o;
    cursor[i] = o;
}

__global__ __launch_bounds__(256) void sort_kernel(
    const void* __restrict__ edges,
    int* __restrict__ cursor, int* __restrict__ sorted, int n_edges)
{
    const int f = detect_f(edges);
    int e = blockIdx.x * 256 + threadIdx.x;
    if (e >= n_edges) return;
    int d = load_dst(edges, e, n_edges, f);
    int s = load_src(edges, e, f);
    int pos = atomicAdd(&cursor[d], 1);
    sorted[pos] = s;
}

__global__ __launch_bounds__(256) void fused_kernel(
    const float* __restrict__ x,
    const int* __restrict__ sorted,
    const int* __restrict__ deg,
    const int* __restrict__ offs,
    const float* __restrict__ Wl,
    const float* __restrict__ Wr,
    const float* __restrict__ b,
    float* __restrict__ out,
    int n_nodes)
{
    __shared__ float s_m[CH][LSTR];
    __shared__ float s_v[CH][LSTR];

    const int node0 = blockIdx.x * NB;
    const int tid   = threadIdx.x;
    const int wave  = tid >> 6;
    const int lane  = tid & 63;

    for (int nn = 0; nn < 16; ++nn) {
        int n    = wave * 16 + nn;
        int node = node0 + n;
        float a0 = 0.f, a1 = 0.f, x0 = 0.f, x1 = 0.f;
        if (node < n_nodes) {
            const float* xr = x + (long long)node * CH;
            x0 = xr[lane];
            x1 = xr[lane + 64];
            int base = offs[node];
            int dg   = deg[node];
            for (int j0 = 0; j0 < dg; j0 += 64) {
                int m  = min(64, dg - j0);
                int sv = (j0 + lane < dg) ? sorted[base + j0 + lane] : 0;
                int jj = 0;
                for (; jj + 8 <= m; jj += 8) {
                    float v0[8], v1[8];
#pragma unroll
                    for (int u = 0; u < 8; ++u) {
                        int s = __shfl(sv, jj + u);
                        const float* p = x + (long long)s * CH;
                        v0[u] = p[lane];
                        v1[u] = p[lane + 64];
                    }
#pragma unroll
                    for (int u = 0; u < 8; ++u) { a0 += v0[u]; a1 += v1[u]; }
                }
                for (; jj < m; ++jj) {
                    int s = __shfl(sv, jj);
                    const float* p = x + (long long)s * CH;
                    a0 += p[lane];
                    a1 += p[lane + 64];
                }
            }
            float inv = 1.0f / fmaxf((float)dg, 1.0f);
            a0 *= inv; a1 *= inv;
        }
        s_m[lane][n]      = a0;
        s_m[lane + 64][n] = a1;
        s_v[lane][n]      = x0;
        s_v[lane + 64][n] = x1;
    }
    __syncthreads();

    const int cg = (tid & 31) * 4;
    const int ng = (tid >> 5) * 8;

    float acc[8][4];
#pragma unroll
    for (int u = 0; u < 8; ++u)
#pragma unroll
        for (int j = 0; j < 4; ++j) acc[u][j] = 0.f;

#pragma unroll 4
    for (int k = 0; k < CH; ++k) {
        const float* mr = &s_m[k][ng];
        const float* vr = &s_v[k][ng];
        float4 wl = *(const float4*)(Wl + k * CH + cg);
        float4 wr = *(const float4*)(Wr + k * CH + cg);
#pragma unroll
        for (int u = 0; u < 8; ++u) {
            float m  = mr[u];
            float xv = vr[u];
            acc[u][0] += m * wl.x + xv * wr.x;
            acc[u][1] += m * wl.y + xv * wr.y;
            acc[u][2] += m * wl.z + xv * wr.z;
            acc[u][3] += m * wl.w + xv * wr.w;
        }
    }

    float4 bb = *(const float4*)(b + cg);
#pragma unroll
    for (int u = 0; u < 8; ++u) {
        int node = node0 + ng + u;
        if (node < n_nodes) {
            float4 o;
            o.x = fmaxf(acc[u][0] + bb.x, 0.0f);
            o.y = fmaxf(acc[u][1] + bb.y, 0.0f);
            o.z = fmaxf(acc[u][2] + bb.z, 0.0f);
            o.w = fmaxf(acc[u][3] + bb.w, 0.0f);
            *(float4*)(out + (long long)node * CH + cg) = o;
        }
    }
}

__global__ __launch_bounds__(256) void scatter_kernel(
    const float* __restrict__ x, const void* __restrict__ edges,
    float* __restrict__ agg, float* __restrict__ cnt, int n_edges)
{
    const int f = detect_f(edges);
    int e = blockIdx.x * 4 + (threadIdx.x >> 6);
    if (e >= n_edges) return;
    int lane = threadIdx.x & 63;
    long long s = load_src(edges, e, f);
    long long d = load_dst(edges, e, n_edges, f);
    const float* xs = x + s * (long long)CH;
    float*       ad = agg + d * (long long)CH;
    unsafeAtomicAdd(ad + lane,      xs[lane]);
    unsafeAtomicAdd(ad + lane + 64, xs[lane + 64]);
    if (lane == 0) unsafeAtomicAdd(cnt + d, 1.0f);
}

__global__ __launch_bounds__(256) void sage_out_kernel(
    const float* __restrict__ x, const float* agg, const float* __restrict__ cnt,
    const float* __restrict__ Wl, const float* __restrict__ Wr,
    const float* __restrict__ b, float* out, int n_nodes)
{
    __shared__ float s_mean[FB_NB][CH];
    __shared__ float s_x[FB_NB][CH];
    const int node0 = blockIdx.x * FB_NB;
    const int tid   = threadIdx.x;
    for (int i = tid; i < FB_NB * CH; i += 256) {
        int n = i >> 7, c = i & (CH - 1);
        int node = node0 + n;
        float a = 0.0f, xv = 0.0f, inv = 1.0f;
        if (node < n_nodes) {
            inv = 1.0f / fmaxf(cnt[node], 1.0f);
            a  = agg[(long long)node * CH + c];
            xv = x[(long long)node * CH + c];
        }
        s_mean[n][c] = a * inv;
        s_x[n][c]    = xv;
    }
    __syncthreads();
    const int cg = (tid & 31) * 4, nbase = (tid >> 5) * 2;
    float acc0[4] = {0,0,0,0}, acc1[4] = {0,0,0,0};
#pragma unroll 8
    for (int k = 0; k < CH; ++k) {
        float4 wl = *(const float4*)(Wl + k * CH + cg);
        float4 wr = *(const float4*)(Wr + k * CH + cg);
        float m0 = s_mean[nbase][k],   m1 = s_mean[nbase + 1][k];
        float x0 = s_x[nbase][k],      x1 = s_x[nbase + 1][k];
        acc0[0] += m0*wl.x + x0*wr.x;  acc0[1] += m0*wl.y + x0*wr.y;
        acc0[2] += m0*wl.z + x0*wr.z;  acc0[3] += m0*wl.w + x0*wr.w;
        acc1[0] += m1*wl.x + x1*wr.x;  acc1[1] += m1*wl.y + x1*wr.y;
        acc1[2] += m1*wl.z + x1*wr.z;  acc1[3] += m1*wl.w + x1*wr.w;
    }
    float4 bb = *(const float4*)(b + cg);
    int n0 = node0 + nbase, n1 = n0 + 1;
    if (n0 < n_nodes) {
        float4 o = { fmaxf(acc0[0]+bb.x,0.f), fmaxf(acc0[1]+bb.y,0.f),
                     fmaxf(acc0[2]+bb.z,0.f), fmaxf(acc0[3]+bb.w,0.f) };
        *(float4*)(out + (long long)n0 * CH + cg) = o;
    }
    if (n1 < n_nodes) {
        float4 o = { fmaxf(acc1[0]+bb.x,0.f), fmaxf(acc1[1]+bb.y,0.f),
                     fmaxf(acc1[2]+bb.z,0.f), fmaxf(acc1[3]+bb.w,0.f) };
        *(float4*)(out + (long long)n1 * CH + cg) = o;
    }
}

extern "C" void kernel_launch(void* const* d_in, const int* in_sizes, int n_in,
                              void* d_out, int out_size, void* d_ws, size_t ws_size,
                              hipStream_t stream)
{
    const float* x     = (const float*)d_in[0];
    const void*  edges = d_in[1];
    const float* Wl    = (const float*)d_in[2];
    const float* Wr    = (const float*)d_in[3];
    const float* b     = (const float*)d_in[4];
    float*       out   = (float*)d_out;

    const int n_nodes = in_sizes[0] / CH;
    const int n_edges = in_sizes[1] / 2;
    const long long n_x = (long long)n_nodes * CH;

    char* ws = (char*)d_ws;
    const size_t ints_n = (size_t)n_nodes * sizeof(int);
    const int    nscan  = (n_nodes + SC_T * SC_I - 1) / (SC_T * SC_I);
    const int    nbins  = (n_nodes + CSZ - 1) >> CSH;

    // tier-1 layout: offs(n+1) | bbase(513) | btot(512) | gcursor(512) | sorted | xb∪binned | Wt
    const size_t offs_b      = ((size_t)(n_nodes + 1) * sizeof(int) + 255) & ~(size_t)255;
    const size_t bbase_off   = offs_b;
    const size_t btot_off    = bbase_off + (NBMAX + 1) * sizeof(int);
    const size_t gcur_off    = btot_off + NBMAX * sizeof(int);
    const size_t sorted_off  = (gcur_off + NBMAX * sizeof(int) + 255) & ~(size_t)255;
    const size_t xb_off      = (sorted_off + (size_t)n_edges * sizeof(int) + 255) & ~(size_t)255;
    const size_t xb_bytes    = ((size_t)n_x * sizeof(ushort) > (size_t)n_edges * 4)
                             ? (size_t)n_x * sizeof(ushort) : (size_t)n_edges * 4;
    const size_t wt_off      = (xb_off + xb_bytes + 255) & ~(size_t)255;
    const size_t t1_need     = wt_off + (size_t)(CH * 2 * CH) * sizeof(ushort);

    // tier-3 layout (f32 path w/ legacy sort)
    const size_t t3_need = 3 * ints_n + 1024 * sizeof(int) + (size_t)n_edges * sizeof(int);

    if (ws_size >= t1_need && nbins <= NBMAX && n_nodes < (1 << 22)) {
        int*      offs    = (int*)ws;
        int*      bbase   = (int*)(ws + bbase_off);
        int*      btot    = (int*)(ws + btot_off);
        int*      gcursor = (int*)(ws + gcur_off);
        int*      sorted  = (int*)(ws + sorted_off);
        ushort*   xb      = (ushort*)(ws + xb_off);
        unsigned* binned  = (unsigned*)(ws + xb_off);   // aliases xb until sortfine2 done
        ushort*   Wt      = (ushort*)(ws + wt_off);

        hipMemsetAsync(btot, 0, NBMAX * sizeof(int), stream);

        // NOTE: binned aliases xb, so the cast must come AFTER sortfine2.
        const int hist_blocks = (n_edges + 256 * A1_E - 1) / (256 * A1_E);
        const long long cast_blocks = (n_x + 2047) / 2048;
        const int pb = (int)((cast_blocks > hist_blocks) ? cast_blocks : hist_blocks);

        // 1) coarse histogram only (cast deferred: pass x=null-ish workload split)
        //    We still fuse: prep2 writes xb; binned region is not yet used. Order:
        //    prep2(cast+hist) -> scanb -> bin -> sortfine2. binned aliasing xb would
        //    clobber the cast, so bin/sortfine2 write binned AFTER cast is consumed?
        //    No: fused reads xb at the end. => Give binned its own region instead:
        //    it fits in [sorted_off..] only if sized. Simpler: binned occupies the
        //    Wt tail? Too small. Use separate region appended after Wt if room,
        //    else fall back to cast-after-sort ordering with separate cast kernel.
        const size_t binned_off  = (t1_need + 255) & ~(size_t)255;
        const size_t t1b_need    = binned_off + (size_t)n_edges * 4;
        if (ws_size >= t1b_need) {
            unsigned* binned2 = (unsigned*)(ws + binned_off);
            prep2_kernel<<<pb, 256, 0, stream>>>(edges, btot, n_edges, x, xb, n_x,
                                                 nbins, hist_blocks);
            wt_kernel<<<(CH * 2 * CH + 255) / 256, 256, 0, stream>>>(Wl, Wr, Wt);
            scanb_kernel<<<1, NBMAX, 0, stream>>>(btot, bbase, gcursor, offs,
                                                  nbins, n_edges, n_nodes);
            const int a1b = (n_edges + A1_T * A1_E - 1) / (A1_T * A1_E);
            bin_kernel<<<a1b, A1_T, 0, stream>>>(edges, gcursor, binned2, n_edges, nbins);
            sortfine2_kernel<<<nbins, CSZ, 0, stream>>>(binned2, bbase, offs, sorted, n_nodes);
        } else {
            // binned aliases xb: sort first, cast after.
            prep2_kernel<<<hist_blocks, 256, 0, stream>>>(edges, btot, n_edges,
                                                          x, xb, 0, nbins, hist_blocks);
            scanb_kernel<<<1, NBMAX, 0, stream>>>(btot, bbase, gcursor, offs,
                                                  nbins, n_edges, n_nodes);
            const int a1b = (n_edges + A1_T * A1_E - 1) / (A1_T * A1_E);
            bin_kernel<<<a1b, A1_T, 0, stream>>>(edges, gcursor, binned, n_edges, nbins);
            sortfine2_kernel<<<nbins, CSZ, 0, stream>>>(binned, bbase, offs, sorted, n_nodes);
            prep2_kernel<<<(int)cast_blocks, 256, 0, stream>>>(edges, btot, n_edges,
                                                               x, xb, n_x, nbins, 0);
            wt_kernel<<<(CH * 2 * CH + 255) / 256, 256, 0, stream>>>(Wl, Wr, Wt);
        }

        const int ntiles = (n_nodes + NB - 1) / NB;
        const int grid   = (ntiles < 2048) ? ntiles : 2048;
        fused_mfma_kernel<<<grid, 256, 0, stream>>>(
            xb, sorted, offs, Wt, b, out, n_nodes, n_edges, ntiles);
    } else if (ws_size >= t3_need && nscan <= 1024) {
        int* deg    = (int*)ws;
        int* offs   = (int*)(ws + ints_n);
        int* cursor = (int*)(ws + 2 * ints_n);
        int* bsums  = (int*)(ws + 3 * ints_n);
        int* sorted = (int*)(ws + 3 * ints_n + 1024 * sizeof(int));

        hipMemsetAsync(deg, 0, ints_n, stream);
        const int eb = (n_edges + 255) / 256;
        hist_kernel<<<eb, 256, 0, stream>>>(edges, deg, n_edges);
        scan_blocks<<<nscan, SC_T, 0, stream>>>(deg, offs, bsums, n_nodes);
        fixup_kernel<<<(n_nodes + 255) / 256, 256, 0, stream>>>(offs, bsums, cursor, n_nodes);
        sort_kernel<<<eb, 256, 0, stream>>>(edges, cursor, sorted, n_edges);
        fused_kernel<<<(n_nodes + NB - 1) / NB, 256, 0, stream>>>(
            x, sorted, deg, offs, Wl, Wr, b, out, n_nodes);
    } else {
        float* agg = out;
        float* cnt = (float*)ws;
        hipMemsetAsync(agg, 0, (size_t)n_nodes * CH * sizeof(float), stream);
        hipMemsetAsync(cnt, 0, ints_n, stream);
        scatter_kernel<<<(n_edges + 3) / 4, 256, 0, stream>>>(x, edges, agg, cnt, n_edges);
        sage_out_kernel<<<(n_nodes + FB_NB - 1) / FB_NB, 256, 0, stream>>>(x, agg, cnt, Wl, Wr, b, out, n_nodes);
    }
}

// Round 9
// 175.765 us; speedup vs baseline: 1.9665x; 1.9665x over previous
//
#include <hip/hip_runtime.h>

#define CH 128
#define NB 64
#define LPAD 4
#define LSTR (NB + LPAD)
#define FB_NB 16
#define SC_T 256
#define SC_I 8
#define CSH 9
#define CSZ 512            // nodes per coarse bucket
#define NBMAX 512          // max coarse buckets (n_nodes <= 262144)
#define A1_T 1024
#define A1_E 8             // edges per thread in bin_kernel

typedef __attribute__((ext_vector_type(8))) __bf16 bf16x8;
typedef __attribute__((ext_vector_type(4))) float f32x4;

// ---------------------------------------------------------------------------
// bf16 helpers (RNE)
// ---------------------------------------------------------------------------
__device__ __forceinline__ unsigned bf16rne(float f) {
    unsigned u = __float_as_uint(f);
    return (u + 0x7FFFu + ((u >> 16) & 1u)) >> 16;
}
__device__ __forceinline__ unsigned pack2bf(float lo, float hi) {
    return bf16rne(lo) | (bf16rne(hi) << 16);
}

// int64-vs-int32 edge_index detection (odd words all zero => int64 < 2^31)
__device__ __forceinline__ int detect_f(const void* edges) {
    const int* ei = (const int*)edges;
    int hi_zero = (ei[1] == 0) & (ei[3] == 0) & (ei[5] == 0) & (ei[7] == 0);
    int lo_any  = (ei[0] | ei[2] | ei[4] | ei[6]) != 0;
    return hi_zero & lo_any;
}
__device__ __forceinline__ int load_dst(const void* edges, int e, int n_edges, int f) {
    const int* p = (const int*)edges;
    return f ? p[2 * (e + n_edges)] : p[e + n_edges];
}
__device__ __forceinline__ int load_src(const void* edges, int e, int f) {
    const int* p = (const int*)edges;
    return f ? p[2 * e] : p[e];
}

// ---------------------------------------------------------------------------
// prep2: coarse-bucket histogram (LDS, 512 bins) + x -> bf16 cast
// ---------------------------------------------------------------------------
__global__ __launch_bounds__(256) void prep2_kernel(
    const void* __restrict__ edges, int* __restrict__ btot, int n_edges,
    const float* __restrict__ x, ushort* __restrict__ xb, long long n_x,
    int nbins, int hist_blocks)
{
    __shared__ int lh[NBMAX];
    const int blk = blockIdx.x, tid = threadIdx.x;
    if (blk < hist_blocks) {
        for (int i = tid; i < nbins; i += 256) lh[i] = 0;
        __syncthreads();
        const int f  = detect_f(edges);
        const int e0 = blk * (256 * A1_E) + tid;
#pragma unroll
        for (int j = 0; j < A1_E; ++j) {
            int e = e0 + j * 256;
            if (e < n_edges) atomicAdd(&lh[load_dst(edges, e, n_edges, f) >> CSH], 1);
        }
        __syncthreads();
        for (int i = tid; i < nbins; i += 256)
            if (lh[i]) atomicAdd(&btot[i], lh[i]);
    }
    long long i = (long long)blk * 256 + tid;
    long long base = i * 8;
    if (base + 8 <= n_x) {
        float4 a = *(const float4*)(x + base);
        float4 c = *(const float4*)(x + base + 4);
        uint4 o;
        o.x = pack2bf(a.x, a.y);
        o.y = pack2bf(a.z, a.w);
        o.z = pack2bf(c.x, c.y);
        o.w = pack2bf(c.z, c.w);
        *(uint4*)(xb + base) = o;
    } else {
        for (long long j = base; j < n_x; ++j) xb[j] = (ushort)bf16rne(x[j]);
    }
}

// W transpose+cast: Wt[j][k] (j=out ch, k=0..255; k<128 -> Wl, else Wr), bf16
__global__ __launch_bounds__(256) void wt_kernel(
    const float* __restrict__ Wl, const float* __restrict__ Wr,
    ushort* __restrict__ Wt)
{
    int idx = blockIdx.x * 256 + threadIdx.x;
    if (idx >= CH * 2 * CH) return;
    int j = idx >> 8, k = idx & 255;
    float v = (k < CH) ? Wl[k * CH + j] : Wr[(k - CH) * CH + j];
    Wt[idx] = (ushort)bf16rne(v);
}

// ---------------------------------------------------------------------------
// 1-block scan of bucket totals -> bbase / gcursor; sentinels.
// ---------------------------------------------------------------------------
__global__ __launch_bounds__(NBMAX) void scanb_kernel(
    const int* __restrict__ btot, int* __restrict__ bbase,
    int* __restrict__ gcursor, int* __restrict__ offs,
    int nbins, int n_edges, int n_nodes)
{
    __shared__ int s[NBMAX];
    const int t = threadIdx.x;
    int v = (t < nbins) ? btot[t] : 0;
    s[t] = v;
    __syncthreads();
    for (int off = 1; off < NBMAX; off <<= 1) {
        int val = (t >= off) ? s[t - off] : 0;
        __syncthreads();
        s[t] += val;
        __syncthreads();
    }
    int excl = s[t] - v;
    if (t < nbins) { bbase[t] = excl; gcursor[t] = excl; }
    if (t == 0) { bbase[nbins] = n_edges; offs[n_nodes] = n_edges; }
}

// ---------------------------------------------------------------------------
// bin edges into coarse buckets with LDS histogram + run reservation.
// entry = src | (dst & 511) << 22   (requires n_nodes < 2^22)
// ---------------------------------------------------------------------------
__global__ __launch_bounds__(A1_T) void bin_kernel(
    const void* __restrict__ edges, int* __restrict__ gcursor,
    unsigned* __restrict__ binned, int n_edges, int nbins)
{
    __shared__ int lcnt[NBMAX];
    __shared__ int lbase[NBMAX];
    const int f   = detect_f(edges);
    const int tid = threadIdx.x;
    for (int i = tid; i < nbins; i += A1_T) lcnt[i] = 0;
    __syncthreads();

    int bin[A1_E], lrank[A1_E];
    unsigned ent[A1_E];
    const int e0 = blockIdx.x * (A1_T * A1_E);
#pragma unroll
    for (int j = 0; j < A1_E; ++j) {
        int e = e0 + j * A1_T + tid;
        bin[j] = -1;
        if (e < n_edges) {
            int s = load_src(edges, e, f);
            int d = load_dst(edges, e, n_edges, f);
            bin[j]   = d >> CSH;
            ent[j]   = (unsigned)s | ((unsigned)(d & (CSZ - 1)) << 22);
            lrank[j] = atomicAdd(&lcnt[bin[j]], 1);
        }
    }
    __syncthreads();
    for (int i = tid; i < nbins; i += A1_T)
        lbase[i] = atomicAdd(&gcursor[i], lcnt[i]);
    __syncthreads();
#pragma unroll
    for (int j = 0; j < A1_E; ++j)
        if (bin[j] >= 0) binned[lbase[bin[j]] + lrank[j]] = ent[j];
}

// ---------------------------------------------------------------------------
// per-bucket: LDS count -> LDS scan -> write offs -> place into sorted.
// All writes in the block-exclusive window [bbase[c], bbase[c+1]).
// ---------------------------------------------------------------------------
__global__ __launch_bounds__(CSZ) void sortfine2_kernel(
    const unsigned* __restrict__ binned, const int* __restrict__ bbase,
    int* __restrict__ offs, int* __restrict__ sorted, int n_nodes)
{
    __shared__ int cnt[CSZ];
    __shared__ int sc[CSZ];
    __shared__ int cur[CSZ];
    const int c   = blockIdx.x;
    const int tid = threadIdx.x;
    cnt[tid] = 0;
    __syncthreads();
    const int start = bbase[c];
    const int end   = bbase[c + 1];
    for (int i = start + tid; i < end; i += CSZ)
        atomicAdd(&cnt[(binned[i] >> 22) & (CSZ - 1)], 1);
    __syncthreads();
    int v = cnt[tid];
    sc[tid] = v;
    __syncthreads();
    for (int off = 1; off < CSZ; off <<= 1) {
        int val = (tid >= off) ? sc[tid - off] : 0;
        __syncthreads();
        sc[tid] += val;
        __syncthreads();
    }
    int gpos = start + sc[tid] - v;        // global start of this node's range
    int node = (c << CSH) + tid;
    if (node < n_nodes) offs[node] = gpos;
    cur[tid] = gpos;
    __syncthreads();
    for (int i = start + tid; i < end; i += CSZ) {
        unsigned ent = binned[i];
        int r = atomicAdd(&cur[(ent >> 22) & (CSZ - 1)], 1);
        sorted[r] = (int)(ent & 0x3FFFFFu);
    }
}

// ---------------------------------------------------------------------------
// persistent fused gather-mean + MFMA GEMM (round-7 proven structure:
// s_m + s_v LDS staging, launch_bounds(256,4), plain __shfl; degree from
// offs diffs, offs has sentinel at n_nodes).
// ---------------------------------------------------------------------------
__global__ __launch_bounds__(256, 4) void fused_mfma_kernel(
    const ushort* __restrict__ xb,
    const int* __restrict__ sorted,
    const int* __restrict__ offs,
    const ushort* __restrict__ Wt,
    const float* __restrict__ bias,
    float* __restrict__ out,
    int n_nodes, int nE, int ntiles)
{
    __shared__ ushort s_m[64][136];
    __shared__ ushort s_v[64][136];

    const int tid  = threadIdx.x;
    const int wave = tid >> 6;
    const int lane = tid & 63;
    const int rA   = lane & 15;
    const int gA   = lane >> 4;
    const int oc0  = wave * 32;
    const float b0 = bias[oc0 + rA];
    const float b1 = bias[oc0 + 16 + rA];

    for (int tile = blockIdx.x; tile < ntiles; tile += gridDim.x) {
        const int node0 = tile * NB;
        const int first = node0 + wave * 16;

        if (first < n_nodes) {
            const int nval = min(16, n_nodes - first);

#pragma unroll
            for (int nn = 0; nn < 16; ++nn) {
                int node = min(first + nn, n_nodes - 1);
                unsigned u = *(const unsigned*)(xb + (size_t)node * CH + lane * 2);
                *(unsigned*)&s_v[wave * 16 + nn][lane * 2] = u;
            }

            const int base0 = offs[first];
            const int e_end = offs[first + nval];
            const int Ew      = e_end - base0;
            const int nb_full = Ew >> 4;
            const int rem     = Ew & 15;

            int   nstored   = 0;
            int   cur_start = base0;
            int   cur_end   = offs[first + 1];
            float alo = 0.f, ahi = 0.f;

            int sv_cur = 0, sv_nxt = 0;
            if (Ew > 0) sv_cur = sorted[min(base0 + lane, nE - 1)];

            auto flushfn = [&](int ii) {
                while (ii == cur_end && nstored < nval) {
                    float sc = 1.0f / fmaxf((float)(cur_end - cur_start), 1.0f);
                    *(unsigned*)&s_m[wave * 16 + nstored][lane * 2] =
                        pack2bf(alo * sc, ahi * sc);
                    alo = 0.f; ahi = 0.f;
                    ++nstored;
                    if (nstored < nval) {
                        cur_start = cur_end;
                        cur_end   = offs[first + nstored + 1];
                    }
                }
            };
            auto issue = [&](unsigned (&U)[16], int bb) {
                if ((bb & 3) == 0) {
                    if (bb > 0) sv_cur = sv_nxt;
                    int c = (bb >> 2) + 1;
                    if (c * 64 < Ew) sv_nxt = sorted[min(base0 + c * 64 + lane, nE - 1)];
                }
                int q = (bb & 3) * 16;
#pragma unroll
                for (int t = 0; t < 16; ++t) {
                    int s = __shfl(sv_cur, q + t);
                    U[t] = *(const unsigned*)(xb + (size_t)s * CH + lane * 2);
                }
            };
            auto accum = [&](unsigned (&U)[16], int bb) {
                int i0 = base0 + bb * 16;
#pragma unroll
                for (int t = 0; t < 16; ++t) {
                    flushfn(i0 + t);
                    alo += __uint_as_float(U[t] << 16);
                    ahi += __uint_as_float(U[t] & 0xFFFF0000u);
                }
            };

            unsigned uA[16], uB[16];
            if (nb_full > 0) issue(uA, 0);
            int bI = 0;
            while (bI < nb_full) {
                if (bI + 1 < nb_full) issue(uB, bI + 1);
                accum(uA, bI);
                ++bI;
                if (bI >= nb_full) break;
                if (bI + 1 < nb_full) issue(uA, bI + 1);
                accum(uB, bI);
                ++bI;
            }

            if (rem > 0) {
                if (nb_full > 0 && (nb_full & 3) == 0) sv_cur = sv_nxt;
                int q = (nb_full & 3) * 16;
                for (int t = 0; t < rem; ++t) {
                    int i = base0 + nb_full * 16 + t;
                    int s = __shfl(sv_cur, q + t);
                    unsigned u = *(const unsigned*)(xb + (size_t)s * CH + lane * 2);
                    flushfn(i);
                    alo += __uint_as_float(u << 16);
                    ahi += __uint_as_float(u & 0xFFFF0000u);
                }
            }
            while (nstored < nval) {
                float sc = 1.0f / fmaxf((float)(cur_end - cur_start), 1.0f);
                *(unsigned*)&s_m[wave * 16 + nstored][lane * 2] =
                    pack2bf(alo * sc, ahi * sc);
                alo = 0.f; ahi = 0.f;
                ++nstored;
                if (nstored < nval) {
                    cur_start = cur_end;
                    cur_end   = offs[first + nstored + 1];
                }
            }
        }
        __syncthreads();

        f32x4 acc[4][2];
#pragma unroll
        for (int nt = 0; nt < 4; ++nt) {
            acc[nt][0] = (f32x4){0.f, 0.f, 0.f, 0.f};
            acc[nt][1] = (f32x4){0.f, 0.f, 0.f, 0.f};
        }

#pragma unroll
        for (int ks = 0; ks < 8; ++ks) {
            const int kk = (ks & 3) * 32 + gA * 8;
            const ushort (*S)[136] = (ks < 4) ? s_m : s_v;
            const ushort* wrow = Wt + ks * 32 + gA * 8;
            bf16x8 bf0 = __builtin_bit_cast(bf16x8,
                *(const uint4*)(wrow + (oc0 + rA) * 256));
            bf16x8 bf1 = __builtin_bit_cast(bf16x8,
                *(const uint4*)(wrow + (oc0 + 16 + rA) * 256));
#pragma unroll
            for (int nt = 0; nt < 4; ++nt) {
                bf16x8 af = __builtin_bit_cast(bf16x8,
                    *(const uint4*)&S[nt * 16 + rA][kk]);
                acc[nt][0] = __builtin_amdgcn_mfma_f32_16x16x32_bf16(af, bf0, acc[nt][0], 0, 0, 0);
                acc[nt][1] = __builtin_amdgcn_mfma_f32_16x16x32_bf16(af, bf1, acc[nt][1], 0, 0, 0);
            }
        }

#pragma unroll
        for (int nt = 0; nt < 4; ++nt) {
            int nbase = node0 + nt * 16 + gA * 4;
#pragma unroll
            for (int r = 0; r < 4; ++r) {
                int node = nbase + r;
                if (node < n_nodes) {
                    out[(size_t)node * CH + oc0 + rA]      = fmaxf(acc[nt][0][r] + b0, 0.f);
                    out[(size_t)node * CH + oc0 + 16 + rA] = fmaxf(acc[nt][1][r] + b1, 0.f);
                }
            }
        }
        __syncthreads();
    }
}

// ---------------------------------------------------------------------------
// legacy helpers for fallback tiers
// ---------------------------------------------------------------------------
__global__ __launch_bounds__(256) void hist_kernel(
    const void* __restrict__ edges, int* __restrict__ deg, int n_edges)
{
    const int f = detect_f(edges);
    int e = blockIdx.x * 256 + threadIdx.x;
    if (e >= n_edges) return;
    atomicAdd(&deg[load_dst(edges, e, n_edges, f)], 1);
}

__global__ __launch_bounds__(SC_T) void scan_blocks(
    const int* __restrict__ deg, int* __restrict__ offs,
    int* __restrict__ bsums, int n)
{
    __shared__ int s_sum[SC_T];
    const int t = threadIdx.x;
    const int base = blockIdx.x * SC_T * SC_I + t * SC_I;
    int v[SC_I];
    int tsum = 0;
#pragma unroll
    for (int i = 0; i < SC_I; ++i) {
        int idx = base + i;
        v[i] = (idx < n) ? deg[idx] : 0;
        tsum += v[i];
    }
    s_sum[t] = tsum;
    __syncthreads();
    for (int off = 1; off < SC_T; off <<= 1) {
        int val = (t >= off) ? s_sum[t - off] : 0;
        __syncthreads();
        s_sum[t] += val;
        __syncthreads();
    }
    int run = s_sum[t] - tsum;
#pragma unroll
    for (int i = 0; i < SC_I; ++i) {
        int idx = base + i;
        if (idx < n) offs[idx] = run;
        run += v[i];
    }
    if (t == SC_T - 1) bsums[blockIdx.x] = s_sum[t];
}

__global__ __launch_bounds__(256) void fixup_kernel(
    int* __restrict__ offs, const int* __restrict__ bsums,
    int* __restrict__ cursor, int n)
{
    int i = blockIdx.x * 256 + threadIdx.x;
    if (i >= n) return;
    int bucket = i / (SC_T * SC_I);
    int add = 0;
    for (int j = 0; j < bucket; ++j) add += bsums[j];
    int o = offs[i] + add;
    offs[i] = o;
    cursor[i] = o;
}

__global__ __launch_bounds__(256) void sort_kernel(
    const void* __restrict__ edges,
    int* __restrict__ cursor, int* __restrict__ sorted, int n_edges)
{
    const int f = detect_f(edges);
    int e = blockIdx.x * 256 + threadIdx.x;
    if (e >= n_edges) return;
    int d = load_dst(edges, e, n_edges, f);
    int s = load_src(edges, e, f);
    int pos = atomicAdd(&cursor[d], 1);
    sorted[pos] = s;
}

__global__ __launch_bounds__(256) void fused_kernel(
    const float* __restrict__ x,
    const int* __restrict__ sorted,
    const int* __restrict__ deg,
    const int* __restrict__ offs,
    const float* __restrict__ Wl,
    const float* __restrict__ Wr,
    const float* __restrict__ b,
    float* __restrict__ out,
    int n_nodes)
{
    __shared__ float s_m[CH][LSTR];
    __shared__ float s_v[CH][LSTR];

    const int node0 = blockIdx.x * NB;
    const int tid   = threadIdx.x;
    const int wave  = tid >> 6;
    const int lane  = tid & 63;

    for (int nn = 0; nn < 16; ++nn) {
        int n    = wave * 16 + nn;
        int node = node0 + n;
        float a0 = 0.f, a1 = 0.f, x0 = 0.f, x1 = 0.f;
        if (node < n_nodes) {
            const float* xr = x + (long long)node * CH;
            x0 = xr[lane];
            x1 = xr[lane + 64];
            int base = offs[node];
            int dg   = deg[node];
            for (int j0 = 0; j0 < dg; j0 += 64) {
                int m  = min(64, dg - j0);
                int sv = (j0 + lane < dg) ? sorted[base + j0 + lane] : 0;
                int jj = 0;
                for (; jj + 8 <= m; jj += 8) {
                    float v0[8], v1[8];
#pragma unroll
                    for (int u = 0; u < 8; ++u) {
                        int s = __shfl(sv, jj + u);
                        const float* p = x + (long long)s * CH;
                        v0[u] = p[lane];
                        v1[u] = p[lane + 64];
                    }
#pragma unroll
                    for (int u = 0; u < 8; ++u) { a0 += v0[u]; a1 += v1[u]; }
                }
                for (; jj < m; ++jj) {
                    int s = __shfl(sv, jj);
                    const float* p = x + (long long)s * CH;
                    a0 += p[lane];
                    a1 += p[lane + 64];
                }
            }
            float inv = 1.0f / fmaxf((float)dg, 1.0f);
            a0 *= inv; a1 *= inv;
        }
        s_m[lane][n]      = a0;
        s_m[lane + 64][n] = a1;
        s_v[lane][n]      = x0;
        s_v[lane + 64][n] = x1;
    }
    __syncthreads();

    const int cg = (tid & 31) * 4;
    const int ng = (tid >> 5) * 8;

    float acc[8][4];
#pragma unroll
    for (int u = 0; u < 8; ++u)
#pragma unroll
        for (int j = 0; j < 4; ++j) acc[u][j] = 0.f;

#pragma unroll 4
    for (int k = 0; k < CH; ++k) {
        const float* mr = &s_m[k][ng];
        const float* vr = &s_v[k][ng];
        float4 wl = *(const float4*)(Wl + k * CH + cg);
        float4 wr = *(const float4*)(Wr + k * CH + cg);
#pragma unroll
        for (int u = 0; u < 8; ++u) {
            float m  = mr[u];
            float xv = vr[u];
            acc[u][0] += m * wl.x + xv * wr.x;
            acc[u][1] += m * wl.y + xv * wr.y;
            acc[u][2] += m * wl.z + xv * wr.z;
            acc[u][3] += m * wl.w + xv * wr.w;
        }
    }

    float4 bb = *(const float4*)(b + cg);
#pragma unroll
    for (int u = 0; u < 8; ++u) {
        int node = node0 + ng + u;
        if (node < n_nodes) {
            float4 o;
            o.x = fmaxf(acc[u][0] + bb.x, 0.0f);
            o.y = fmaxf(acc[u][1] + bb.y, 0.0f);
            o.z = fmaxf(acc[u][2] + bb.z, 0.0f);
            o.w = fmaxf(acc[u][3] + bb.w, 0.0f);
            *(float4*)(out + (long long)node * CH + cg) = o;
        }
    }
}

__global__ __launch_bounds__(256) void scatter_kernel(
    const float* __restrict__ x, const void* __restrict__ edges,
    float* __restrict__ agg, float* __restrict__ cnt, int n_edges)
{
    const int f = detect_f(edges);
    int e = blockIdx.x * 4 + (threadIdx.x >> 6);
    if (e >= n_edges) return;
    int lane = threadIdx.x & 63;
    long long s = load_src(edges, e, f);
    long long d = load_dst(edges, e, n_edges, f);
    const float* xs = x + s * (long long)CH;
    float*       ad = agg + d * (long long)CH;
    unsafeAtomicAdd(ad + lane,      xs[lane]);
    unsafeAtomicAdd(ad + lane + 64, xs[lane + 64]);
    if (lane == 0) unsafeAtomicAdd(cnt + d, 1.0f);
}

__global__ __launch_bounds__(256) void sage_out_kernel(
    const float* __restrict__ x, const float* agg, const float* __restrict__ cnt,
    const float* __restrict__ Wl, const float* __restrict__ Wr,
    const float* __restrict__ b, float* out, int n_nodes)
{
    __shared__ float s_mean[FB_NB][CH];
    __shared__ float s_x[FB_NB][CH];
    const int node0 = blockIdx.x * FB_NB;
    const int tid   = threadIdx.x;
    for (int i = tid; i < FB_NB * CH; i += 256) {
        int n = i >> 7, c = i & (CH - 1);
        int node = node0 + n;
        float a = 0.0f, xv = 0.0f, inv = 1.0f;
        if (node < n_nodes) {
            inv = 1.0f / fmaxf(cnt[node], 1.0f);
            a  = agg[(long long)node * CH + c];
            xv = x[(long long)node * CH + c];
        }
        s_mean[n][c] = a * inv;
        s_x[n][c]    = xv;
    }
    __syncthreads();
    const int cg = (tid & 31) * 4, nbase = (tid >> 5) * 2;
    float acc0[4] = {0,0,0,0}, acc1[4] = {0,0,0,0};
#pragma unroll 8
    for (int k = 0; k < CH; ++k) {
        float4 wl = *(const float4*)(Wl + k * CH + cg);
        float4 wr = *(const float4*)(Wr + k * CH + cg);
        float m0 = s_mean[nbase][k],   m1 = s_mean[nbase + 1][k];
        float x0 = s_x[nbase][k],      x1 = s_x[nbase + 1][k];
        acc0[0] += m0*wl.x + x0*wr.x;  acc0[1] += m0*wl.y + x0*wr.y;
        acc0[2] += m0*wl.z + x0*wr.z;  acc0[3] += m0*wl.w + x0*wr.w;
        acc1[0] += m1*wl.x + x1*wr.x;  acc1[1] += m1*wl.y + x1*wr.y;
        acc1[2] += m1*wl.z + x1*wr.z;  acc1[3] += m1*wl.w + x1*wr.w;
    }
    float4 bb = *(const float4*)(b + cg);
    int n0 = node0 + nbase, n1 = n0 + 1;
    if (n0 < n_nodes) {
        float4 o = { fmaxf(acc0[0]+bb.x,0.f), fmaxf(acc0[1]+bb.y,0.f),
                     fmaxf(acc0[2]+bb.z,0.f), fmaxf(acc0[3]+bb.w,0.f) };
        *(float4*)(out + (long long)n0 * CH + cg) = o;
    }
    if (n1 < n_nodes) {
        float4 o = { fmaxf(acc1[0]+bb.x,0.f), fmaxf(acc1[1]+bb.y,0.f),
                     fmaxf(acc1[2]+bb.z,0.f), fmaxf(acc1[3]+bb.w,0.f) };
        *(float4*)(out + (long long)n1 * CH + cg) = o;
    }
}

extern "C" void kernel_launch(void* const* d_in, const int* in_sizes, int n_in,
                              void* d_out, int out_size, void* d_ws, size_t ws_size,
                              hipStream_t stream)
{
    const float* x     = (const float*)d_in[0];
    const void*  edges = d_in[1];
    const float* Wl    = (const float*)d_in[2];
    const float* Wr    = (const float*)d_in[3];
    const float* b     = (const float*)d_in[4];
    float*       out   = (float*)d_out;

    const int n_nodes = in_sizes[0] / CH;
    const int n_edges = in_sizes[1] / 2;
    const long long n_x = (long long)n_nodes * CH;

    char* ws = (char*)d_ws;
    const size_t ints_n = (size_t)n_nodes * sizeof(int);
    const int    nscan  = (n_nodes + SC_T * SC_I - 1) / (SC_T * SC_I);
    const int    nbins  = (n_nodes + CSZ - 1) >> CSH;

    // tier-1 layout: offs(n+1) | bbase(513) | btot(512) | gcursor(512) | sorted | xb∪binned | Wt
    const size_t offs_b      = ((size_t)(n_nodes + 1) * sizeof(int) + 255) & ~(size_t)255;
    const size_t bbase_off   = offs_b;
    const size_t btot_off    = bbase_off + (NBMAX + 1) * sizeof(int);
    const size_t gcur_off    = btot_off + NBMAX * sizeof(int);
    const size_t sorted_off  = (gcur_off + NBMAX * sizeof(int) + 255) & ~(size_t)255;
    const size_t xb_off      = (sorted_off + (size_t)n_edges * sizeof(int) + 255) & ~(size_t)255;
    const size_t xb_bytes    = ((size_t)n_x * sizeof(ushort) > (size_t)n_edges * 4)
                             ? (size_t)n_x * sizeof(ushort) : (size_t)n_edges * 4;
    const size_t wt_off      = (xb_off + xb_bytes + 255) & ~(size_t)255;
    const size_t t1_need     = wt_off + (size_t)(CH * 2 * CH) * sizeof(ushort);

    // tier-3 layout (f32 path w/ legacy sort)
    const size_t t3_need = 3 * ints_n + 1024 * sizeof(int) + (size_t)n_edges * sizeof(int);

    if (ws_size >= t1_need && nbins <= NBMAX && n_nodes < (1 << 22)) {
        int*      offs    = (int*)ws;
        int*      bbase   = (int*)(ws + bbase_off);
        int*      btot    = (int*)(ws + btot_off);
        int*      gcursor = (int*)(ws + gcur_off);
        int*      sorted  = (int*)(ws + sorted_off);
        ushort*   xb      = (ushort*)(ws + xb_off);
        unsigned* binned  = (unsigned*)(ws + xb_off);   // aliases xb until sortfine2 done
        ushort*   Wt      = (ushort*)(ws + wt_off);

        hipMemsetAsync(btot, 0, NBMAX * sizeof(int), stream);

        const int hist_blocks = (n_edges + 256 * A1_E - 1) / (256 * A1_E);
        const long long cast_blocks = (n_x + 2047) / 2048;
        const int pb = (int)((cast_blocks > hist_blocks) ? cast_blocks : hist_blocks);

        const size_t binned_off  = (t1_need + 255) & ~(size_t)255;
        const size_t t1b_need    = binned_off + (size_t)n_edges * 4;
        if (ws_size >= t1b_need) {
            // binned has its own region: full fusion (hist+cast in one pass).
            unsigned* binned2 = (unsigned*)(ws + binned_off);
            prep2_kernel<<<pb, 256, 0, stream>>>(edges, btot, n_edges, x, xb, n_x,
                                                 nbins, hist_blocks);
            wt_kernel<<<(CH * 2 * CH + 255) / 256, 256, 0, stream>>>(Wl, Wr, Wt);
            scanb_kernel<<<1, NBMAX, 0, stream>>>(btot, bbase, gcursor, offs,
                                                  nbins, n_edges, n_nodes);
            const int a1b = (n_edges + A1_T * A1_E - 1) / (A1_T * A1_E);
            bin_kernel<<<a1b, A1_T, 0, stream>>>(edges, gcursor, binned2, n_edges, nbins);
            sortfine2_kernel<<<nbins, CSZ, 0, stream>>>(binned2, bbase, offs, sorted, n_nodes);
        } else {
            // binned aliases xb: sort first, cast after.
            prep2_kernel<<<hist_blocks, 256, 0, stream>>>(edges, btot, n_edges,
                                                          x, xb, 0, nbins, hist_blocks);
            scanb_kernel<<<1, NBMAX, 0, stream>>>(btot, bbase, gcursor, offs,
                                                  nbins, n_edges, n_nodes);
            const int a1b = (n_edges + A1_T * A1_E - 1) / (A1_T * A1_E);
            bin_kernel<<<a1b, A1_T, 0, stream>>>(edges, gcursor, binned, n_edges, nbins);
            sortfine2_kernel<<<nbins, CSZ, 0, stream>>>(binned, bbase, offs, sorted, n_nodes);
            prep2_kernel<<<(int)cast_blocks, 256, 0, stream>>>(edges, btot, n_edges,
                                                               x, xb, n_x, nbins, 0);
            wt_kernel<<<(CH * 2 * CH + 255) / 256, 256, 0, stream>>>(Wl, Wr, Wt);
        }

        const int ntiles = (n_nodes + NB - 1) / NB;
        const int grid   = (ntiles < 1024) ? ntiles : 1024;
        fused_mfma_kernel<<<grid, 256, 0, stream>>>(
            xb, sorted, offs, Wt, b, out, n_nodes, n_edges, ntiles);
    } else if (ws_size >= t3_need && nscan <= 1024) {
        int* deg    = (int*)ws;
        int* offs   = (int*)(ws + ints_n);
        int* cursor = (int*)(ws + 2 * ints_n);
        int* bsums  = (int*)(ws + 3 * ints_n);
        int* sorted = (int*)(ws + 3 * ints_n + 1024 * sizeof(int));

        hipMemsetAsync(deg, 0, ints_n, stream);
        const int eb = (n_edges + 255) / 256;
        hist_kernel<<<eb, 256, 0, stream>>>(edges, deg, n_edges);
        scan_blocks<<<nscan, SC_T, 0, stream>>>(deg, offs, bsums, n_nodes);
        fixup_kernel<<<(n_nodes + 255) / 256, 256, 0, stream>>>(offs, bsums, cursor, n_nodes);
        sort_kernel<<<eb, 256, 0, stream>>>(edges, cursor, sorted, n_edges);
        fused_kernel<<<(n_nodes + NB - 1) / NB, 256, 0, stream>>>(
            x, sorted, deg, offs, Wl, Wr, b, out, n_nodes);
    } else {
        float* agg = out;
        float* cnt = (float*)ws;
        hipMemsetAsync(agg, 0, (size_t)n_nodes * CH * sizeof(float), stream);
        hipMemsetAsync(cnt, 0, ints_n, stream);
        scatter_kernel<<<(n_edges + 3) / 4, 256, 0, stream>>>(x, edges, agg, cnt, n_edges);
        sage_out_kernel<<<(n_nodes + FB_NB - 1) / FB_NB, 256, 0, stream>>>(x, agg, cnt, Wl, Wr, b, out, n_nodes);
    }
}

// Round 10
// 162.233 us; speedup vs baseline: 2.1305x; 1.0834x over previous
//
#include <hip/hip_runtime.h>

#define CH 128
#define NB 64
#define LPAD 4
#define LSTR (NB + LPAD)
#define FB_NB 16
#define SC_T 256
#define SC_I 8
#define CSH 9
#define CSZ 512            // nodes per coarse bucket
#define NBMAX 512          // max coarse buckets (n_nodes <= 262144)
#define A1_T 1024
#define A1_E 8             // edges per thread in bin_kernel

typedef __attribute__((ext_vector_type(8))) __bf16 bf16x8;
typedef __attribute__((ext_vector_type(4))) float f32x4;

// ---------------------------------------------------------------------------
// bf16 helpers (RNE)
// ---------------------------------------------------------------------------
__device__ __forceinline__ unsigned bf16rne(float f) {
    unsigned u = __float_as_uint(f);
    return (u + 0x7FFFu + ((u >> 16) & 1u)) >> 16;
}
__device__ __forceinline__ unsigned pack2bf(float lo, float hi) {
    return bf16rne(lo) | (bf16rne(hi) << 16);
}

// int64-vs-int32 edge_index detection (odd words all zero => int64 < 2^31)
__device__ __forceinline__ int detect_f(const void* edges) {
    const int* ei = (const int*)edges;
    int hi_zero = (ei[1] == 0) & (ei[3] == 0) & (ei[5] == 0) & (ei[7] == 0);
    int lo_any  = (ei[0] | ei[2] | ei[4] | ei[6]) != 0;
    return hi_zero & lo_any;
}
__device__ __forceinline__ int load_dst(const void* edges, int e, int n_edges, int f) {
    const int* p = (const int*)edges;
    return f ? p[2 * (e + n_edges)] : p[e + n_edges];
}
__device__ __forceinline__ int load_src(const void* edges, int e, int f) {
    const int* p = (const int*)edges;
    return f ? p[2 * e] : p[e];
}

// ---------------------------------------------------------------------------
// prep2: coarse-bucket histogram (LDS, 512 bins) + x -> bf16 cast
//        + (optional) W transpose/cast fused into the first 128 blocks.
// ---------------------------------------------------------------------------
__global__ __launch_bounds__(256) void prep2_kernel(
    const void* __restrict__ edges, int* __restrict__ btot, int n_edges,
    const float* __restrict__ x, ushort* __restrict__ xb, long long n_x,
    int nbins, int hist_blocks,
    const float* __restrict__ Wl, const float* __restrict__ Wr,
    ushort* __restrict__ Wt, int do_wt)
{
    __shared__ int lh[NBMAX];
    const int blk = blockIdx.x, tid = threadIdx.x;
    if (blk < hist_blocks) {
        for (int i = tid; i < nbins; i += 256) lh[i] = 0;
        __syncthreads();
        const int f  = detect_f(edges);
        const int e0 = blk * (256 * A1_E) + tid;
#pragma unroll
        for (int j = 0; j < A1_E; ++j) {
            int e = e0 + j * 256;
            if (e < n_edges) atomicAdd(&lh[load_dst(edges, e, n_edges, f) >> CSH], 1);
        }
        __syncthreads();
        for (int i = tid; i < nbins; i += 256)
            if (lh[i]) atomicAdd(&btot[i], lh[i]);
    }
    long long i = (long long)blk * 256 + tid;
    long long base = i * 8;
    if (base + 8 <= n_x) {
        float4 a = *(const float4*)(x + base);
        float4 c = *(const float4*)(x + base + 4);
        uint4 o;
        o.x = pack2bf(a.x, a.y);
        o.y = pack2bf(a.z, a.w);
        o.z = pack2bf(c.x, c.y);
        o.w = pack2bf(c.z, c.w);
        *(uint4*)(xb + base) = o;
    } else {
        for (long long j = base; j < n_x; ++j) xb[j] = (ushort)bf16rne(x[j]);
    }
    if (do_wt) {
        int idx = blk * 256 + tid;
        if (idx < CH * 2 * CH) {
            int j = idx >> 8, k = idx & 255;
            float v = (k < CH) ? Wl[k * CH + j] : Wr[(k - CH) * CH + j];
            Wt[idx] = (ushort)bf16rne(v);
        }
    }
}

// ---------------------------------------------------------------------------
// 1-block scan of bucket totals -> bbase / gcursor; sentinels.
// ---------------------------------------------------------------------------
__global__ __launch_bounds__(NBMAX) void scanb_kernel(
    const int* __restrict__ btot, int* __restrict__ bbase,
    int* __restrict__ gcursor, int* __restrict__ offs,
    int nbins, int n_edges, int n_nodes)
{
    __shared__ int s[NBMAX];
    const int t = threadIdx.x;
    int v = (t < nbins) ? btot[t] : 0;
    s[t] = v;
    __syncthreads();
    for (int off = 1; off < NBMAX; off <<= 1) {
        int val = (t >= off) ? s[t - off] : 0;
        __syncthreads();
        s[t] += val;
        __syncthreads();
    }
    int excl = s[t] - v;
    if (t < nbins) { bbase[t] = excl; gcursor[t] = excl; }
    if (t == 0) { bbase[nbins] = n_edges; offs[n_nodes] = n_edges; }
}

// ---------------------------------------------------------------------------
// bin edges into coarse buckets with LDS histogram + run reservation.
// entry = src | (dst & 511) << 22   (requires n_nodes < 2^22)
// ---------------------------------------------------------------------------
__global__ __launch_bounds__(A1_T) void bin_kernel(
    const void* __restrict__ edges, int* __restrict__ gcursor,
    unsigned* __restrict__ binned, int n_edges, int nbins)
{
    __shared__ int lcnt[NBMAX];
    __shared__ int lbase[NBMAX];
    const int f   = detect_f(edges);
    const int tid = threadIdx.x;
    for (int i = tid; i < nbins; i += A1_T) lcnt[i] = 0;
    __syncthreads();

    int bin[A1_E], lrank[A1_E];
    unsigned ent[A1_E];
    const int e0 = blockIdx.x * (A1_T * A1_E);
#pragma unroll
    for (int j = 0; j < A1_E; ++j) {
        int e = e0 + j * A1_T + tid;
        bin[j] = -1;
        if (e < n_edges) {
            int s = load_src(edges, e, f);
            int d = load_dst(edges, e, n_edges, f);
            bin[j]   = d >> CSH;
            ent[j]   = (unsigned)s | ((unsigned)(d & (CSZ - 1)) << 22);
            lrank[j] = atomicAdd(&lcnt[bin[j]], 1);
        }
    }
    __syncthreads();
    for (int i = tid; i < nbins; i += A1_T)
        lbase[i] = atomicAdd(&gcursor[i], lcnt[i]);
    __syncthreads();
#pragma unroll
    for (int j = 0; j < A1_E; ++j)
        if (bin[j] >= 0) binned[lbase[bin[j]] + lrank[j]] = ent[j];
}

// ---------------------------------------------------------------------------
// per-bucket: LDS count -> LDS scan -> write offs -> place into sorted.
// All writes in the block-exclusive window [bbase[c], bbase[c+1]).
// ---------------------------------------------------------------------------
__global__ __launch_bounds__(CSZ) void sortfine2_kernel(
    const unsigned* __restrict__ binned, const int* __restrict__ bbase,
    int* __restrict__ offs, int* __restrict__ sorted, int n_nodes)
{
    __shared__ int cnt[CSZ];
    __shared__ int sc[CSZ];
    __shared__ int cur[CSZ];
    const int c   = blockIdx.x;
    const int tid = threadIdx.x;
    cnt[tid] = 0;
    __syncthreads();
    const int start = bbase[c];
    const int end   = bbase[c + 1];
    for (int i = start + tid; i < end; i += CSZ)
        atomicAdd(&cnt[(binned[i] >> 22) & (CSZ - 1)], 1);
    __syncthreads();
    int v = cnt[tid];
    sc[tid] = v;
    __syncthreads();
    for (int off = 1; off < CSZ; off <<= 1) {
        int val = (tid >= off) ? sc[tid - off] : 0;
        __syncthreads();
        sc[tid] += val;
        __syncthreads();
    }
    int gpos = start + sc[tid] - v;        // global start of this node's range
    int node = (c << CSH) + tid;
    if (node < n_nodes) offs[node] = gpos;
    cur[tid] = gpos;
    __syncthreads();
    for (int i = start + tid; i < end; i += CSZ) {
        unsigned ent = binned[i];
        int r = atomicAdd(&cur[(ent >> 22) & (CSZ - 1)], 1);
        sorted[r] = (int)(ent & 0x3FFFFFu);
    }
}

// ---------------------------------------------------------------------------
// fused gather-mean + MFMA GEMM. Non-persistent (one 64-node tile per block,
// HW scheduler balances variable tile work). Triple-buffered 16-edge batches
// (named uA/uB/uC -- no dynamic indexing, rule #20). Degree from offs diffs.
// ---------------------------------------------------------------------------
__global__ __launch_bounds__(256, 4) void fused_mfma_kernel(
    const ushort* __restrict__ xb,
    const int* __restrict__ sorted,
    const int* __restrict__ offs,
    const ushort* __restrict__ Wt,
    const float* __restrict__ bias,
    float* __restrict__ out,
    int n_nodes, int nE)
{
    __shared__ ushort s_m[64][136];
    __shared__ ushort s_v[64][136];

    const int tid  = threadIdx.x;
    const int wave = tid >> 6;
    const int lane = tid & 63;
    const int rA   = lane & 15;
    const int gA   = lane >> 4;
    const int oc0  = wave * 32;
    const float b0 = bias[oc0 + rA];
    const float b1 = bias[oc0 + 16 + rA];

    const int node0 = blockIdx.x * NB;
    const int first = node0 + wave * 16;

    if (first < n_nodes) {
        const int nval = min(16, n_nodes - first);

#pragma unroll
        for (int nn = 0; nn < 16; ++nn) {
            int node = min(first + nn, n_nodes - 1);
            unsigned u = *(const unsigned*)(xb + (size_t)node * CH + lane * 2);
            *(unsigned*)&s_v[wave * 16 + nn][lane * 2] = u;
        }

        const int base0 = offs[first];
        const int e_end = offs[first + nval];
        const int Ew      = e_end - base0;
        const int nb_full = Ew >> 4;
        const int rem     = Ew & 15;

        int   nstored   = 0;
        int   cur_start = base0;
        int   cur_end   = offs[first + 1];
        float alo = 0.f, ahi = 0.f;

        int sv_cur = 0, sv_nxt = 0;
        if (Ew > 0) sv_cur = sorted[min(base0 + lane, nE - 1)];

        auto flushfn = [&](int ii) {
            while (ii == cur_end && nstored < nval) {
                float sc = 1.0f / fmaxf((float)(cur_end - cur_start), 1.0f);
                *(unsigned*)&s_m[wave * 16 + nstored][lane * 2] =
                    pack2bf(alo * sc, ahi * sc);
                alo = 0.f; ahi = 0.f;
                ++nstored;
                if (nstored < nval) {
                    cur_start = cur_end;
                    cur_end   = offs[first + nstored + 1];
                }
            }
        };
        auto issue = [&](unsigned (&U)[16], int bb) {
            if ((bb & 3) == 0) {
                if (bb > 0) sv_cur = sv_nxt;
                int c = (bb >> 2) + 1;
                if (c * 64 < Ew) sv_nxt = sorted[min(base0 + c * 64 + lane, nE - 1)];
            }
            int q = (bb & 3) * 16;
#pragma unroll
            for (int t = 0; t < 16; ++t) {
                int s = __shfl(sv_cur, q + t);
                U[t] = *(const unsigned*)(xb + (size_t)s * CH + lane * 2);
            }
        };
        auto accum = [&](unsigned (&U)[16], int bb) {
            int i0 = base0 + bb * 16;
#pragma unroll
            for (int t = 0; t < 16; ++t) {
                flushfn(i0 + t);
                alo += __uint_as_float(U[t] << 16);
                ahi += __uint_as_float(U[t] & 0xFFFF0000u);
            }
        };

        // 3-deep software pipeline: issue runs 2 batches ahead of accum.
        unsigned uA[16], uB[16], uC[16];
        if (nb_full > 0) issue(uA, 0);
        if (nb_full > 1) issue(uB, 1);
        int bI = 0;
        while (bI < nb_full) {
            if (bI + 2 < nb_full) issue(uC, bI + 2);
            accum(uA, bI);
            ++bI; if (bI >= nb_full) break;
            if (bI + 2 < nb_full) issue(uA, bI + 2);
            accum(uB, bI);
            ++bI; if (bI >= nb_full) break;
            if (bI + 2 < nb_full) issue(uB, bI + 2);
            accum(uC, bI);
            ++bI;
        }

        if (rem > 0) {
            if (nb_full > 0 && (nb_full & 3) == 0) sv_cur = sv_nxt;
            int q = (nb_full & 3) * 16;
            for (int t = 0; t < rem; ++t) {
                int i = base0 + nb_full * 16 + t;
                int s = __shfl(sv_cur, q + t);
                unsigned u = *(const unsigned*)(xb + (size_t)s * CH + lane * 2);
                flushfn(i);
                alo += __uint_as_float(u << 16);
                ahi += __uint_as_float(u & 0xFFFF0000u);
            }
        }
        while (nstored < nval) {
            float sc = 1.0f / fmaxf((float)(cur_end - cur_start), 1.0f);
            *(unsigned*)&s_m[wave * 16 + nstored][lane * 2] =
                pack2bf(alo * sc, ahi * sc);
            alo = 0.f; ahi = 0.f;
            ++nstored;
            if (nstored < nval) {
                cur_start = cur_end;
                cur_end   = offs[first + nstored + 1];
            }
        }
    }
    __syncthreads();

    f32x4 acc[4][2];
#pragma unroll
    for (int nt = 0; nt < 4; ++nt) {
        acc[nt][0] = (f32x4){0.f, 0.f, 0.f, 0.f};
        acc[nt][1] = (f32x4){0.f, 0.f, 0.f, 0.f};
    }

#pragma unroll
    for (int ks = 0; ks < 8; ++ks) {
        const int kk = (ks & 3) * 32 + gA * 8;
        const ushort (*S)[136] = (ks < 4) ? s_m : s_v;
        const ushort* wrow = Wt + ks * 32 + gA * 8;
        bf16x8 bf0 = __builtin_bit_cast(bf16x8,
            *(const uint4*)(wrow + (oc0 + rA) * 256));
        bf16x8 bf1 = __builtin_bit_cast(bf16x8,
            *(const uint4*)(wrow + (oc0 + 16 + rA) * 256));
#pragma unroll
        for (int nt = 0; nt < 4; ++nt) {
            bf16x8 af = __builtin_bit_cast(bf16x8,
                *(const uint4*)&S[nt * 16 + rA][kk]);
            acc[nt][0] = __builtin_amdgcn_mfma_f32_16x16x32_bf16(af, bf0, acc[nt][0], 0, 0, 0);
            acc[nt][1] = __builtin_amdgcn_mfma_f32_16x16x32_bf16(af, bf1, acc[nt][1], 0, 0, 0);
        }
    }

#pragma unroll
    for (int nt = 0; nt < 4; ++nt) {
        int nbase = node0 + nt * 16 + gA * 4;
#pragma unroll
        for (int r = 0; r < 4; ++r) {
            int node = nbase + r;
            if (node < n_nodes) {
                out[(size_t)node * CH + oc0 + rA]      = fmaxf(acc[nt][0][r] + b0, 0.f);
                out[(size_t)node * CH + oc0 + 16 + rA] = fmaxf(acc[nt][1][r] + b1, 0.f);
            }
        }
    }
}

// ---------------------------------------------------------------------------
// legacy helpers for fallback tiers
// ---------------------------------------------------------------------------
__global__ __launch_bounds__(256) void hist_kernel(
    const void* __restrict__ edges, int* __restrict__ deg, int n_edges)
{
    const int f = detect_f(edges);
    int e = blockIdx.x * 256 + threadIdx.x;
    if (e >= n_edges) return;
    atomicAdd(&deg[load_dst(edges, e, n_edges, f)], 1);
}

__global__ __launch_bounds__(SC_T) void scan_blocks(
    const int* __restrict__ deg, int* __restrict__ offs,
    int* __restrict__ bsums, int n)
{
    __shared__ int s_sum[SC_T];
    const int t = threadIdx.x;
    const int base = blockIdx.x * SC_T * SC_I + t * SC_I;
    int v[SC_I];
    int tsum = 0;
#pragma unroll
    for (int i = 0; i < SC_I; ++i) {
        int idx = base + i;
        v[i] = (idx < n) ? deg[idx] : 0;
        tsum += v[i];
    }
    s_sum[t] = tsum;
    __syncthreads();
    for (int off = 1; off < SC_T; off <<= 1) {
        int val = (t >= off) ? s_sum[t - off] : 0;
        __syncthreads();
        s_sum[t] += val;
        __syncthreads();
    }
    int run = s_sum[t] - tsum;
#pragma unroll
    for (int i = 0; i < SC_I; ++i) {
        int idx = base + i;
        if (idx < n) offs[idx] = run;
        run += v[i];
    }
    if (t == SC_T - 1) bsums[blockIdx.x] = s_sum[t];
}

__global__ __launch_bounds__(256) void fixup_kernel(
    int* __restrict__ offs, const int* __restrict__ bsums,
    int* __restrict__ cursor, int n)
{
    int i = blockIdx.x * 256 + threadIdx.x;
    if (i >= n) return;
    int bucket = i / (SC_T * SC_I);
    int add = 0;
    for (int j = 0; j < bucket; ++j) add += bsums[j];
    int o = offs[i] + add;
    offs[i] = o;
    cursor[i] = o;
}

__global__ __launch_bounds__(256) void sort_kernel(
    const void* __restrict__ edges,
    int* __restrict__ cursor, int* __restrict__ sorted, int n_edges)
{
    const int f = detect_f(edges);
    int e = blockIdx.x * 256 + threadIdx.x;
    if (e >= n_edges) return;
    int d = load_dst(edges, e, n_edges, f);
    int s = load_src(edges, e, f);
    int pos = atomicAdd(&cursor[d], 1);
    sorted[pos] = s;
}

__global__ __launch_bounds__(256) void fused_kernel(
    const float* __restrict__ x,
    const int* __restrict__ sorted,
    const int* __restrict__ deg,
    const int* __restrict__ offs,
    const float* __restrict__ Wl,
    const float* __restrict__ Wr,
    const float* __restrict__ b,
    float* __restrict__ out,
    int n_nodes)
{
    __shared__ float s_m[CH][LSTR];
    __shared__ float s_v[CH][LSTR];

    const int node0 = blockIdx.x * NB;
    const int tid   = threadIdx.x;
    const int wave  = tid >> 6;
    const int lane  = tid & 63;

    for (int nn = 0; nn < 16; ++nn) {
        int n    = wave * 16 + nn;
        int node = node0 + n;
        float a0 = 0.f, a1 = 0.f, x0 = 0.f, x1 = 0.f;
        if (node < n_nodes) {
            const float* xr = x + (long long)node * CH;
            x0 = xr[lane];
            x1 = xr[lane + 64];
            int base = offs[node];
            int dg   = deg[node];
            for (int j0 = 0; j0 < dg; j0 += 64) {
                int m  = min(64, dg - j0);
                int sv = (j0 + lane < dg) ? sorted[base + j0 + lane] : 0;
                int jj = 0;
                for (; jj + 8 <= m; jj += 8) {
                    float v0[8], v1[8];
#pragma unroll
                    for (int u = 0; u < 8; ++u) {
                        int s = __shfl(sv, jj + u);
                        const float* p = x + (long long)s * CH;
                        v0[u] = p[lane];
                        v1[u] = p[lane + 64];
                    }
#pragma unroll
                    for (int u = 0; u < 8; ++u) { a0 += v0[u]; a1 += v1[u]; }
                }
                for (; jj < m; ++jj) {
                    int s = __shfl(sv, jj);
                    const float* p = x + (long long)s * CH;
                    a0 += p[lane];
                    a1 += p[lane + 64];
                }
            }
            float inv = 1.0f / fmaxf((float)dg, 1.0f);
            a0 *= inv; a1 *= inv;
        }
        s_m[lane][n]      = a0;
        s_m[lane + 64][n] = a1;
        s_v[lane][n]      = x0;
        s_v[lane + 64][n] = x1;
    }
    __syncthreads();

    const int cg = (tid & 31) * 4;
    const int ng = (tid >> 5) * 8;

    float acc[8][4];
#pragma unroll
    for (int u = 0; u < 8; ++u)
#pragma unroll
        for (int j = 0; j < 4; ++j) acc[u][j] = 0.f;

#pragma unroll 4
    for (int k = 0; k < CH; ++k) {
        const float* mr = &s_m[k][ng];
        const float* vr = &s_v[k][ng];
        float4 wl = *(const float4*)(Wl + k * CH + cg);
        float4 wr = *(const float4*)(Wr + k * CH + cg);
#pragma unroll
        for (int u = 0; u < 8; ++u) {
            float m  = mr[u];
            float xv = vr[u];
            acc[u][0] += m * wl.x + xv * wr.x;
            acc[u][1] += m * wl.y + xv * wr.y;
            acc[u][2] += m * wl.z + xv * wr.z;
            acc[u][3] += m * wl.w + xv * wr.w;
        }
    }

    float4 bb = *(const float4*)(b + cg);
#pragma unroll
    for (int u = 0; u < 8; ++u) {
        int node = node0 + ng + u;
        if (node < n_nodes) {
            float4 o;
            o.x = fmaxf(acc[u][0] + bb.x, 0.0f);
            o.y = fmaxf(acc[u][1] + bb.y, 0.0f);
            o.z = fmaxf(acc[u][2] + bb.z, 0.0f);
            o.w = fmaxf(acc[u][3] + bb.w, 0.0f);
            *(float4*)(out + (long long)node * CH + cg) = o;
        }
    }
}

__global__ __launch_bounds__(256) void scatter_kernel(
    const float* __restrict__ x, const void* __restrict__ edges,
    float* __restrict__ agg, float* __restrict__ cnt, int n_edges)
{
    const int f = detect_f(edges);
    int e = blockIdx.x * 4 + (threadIdx.x >> 6);
    if (e >= n_edges) return;
    int lane = threadIdx.x & 63;
    long long s = load_src(edges, e, f);
    long long d = load_dst(edges, e, n_edges, f);
    const float* xs = x + s * (long long)CH;
    float*       ad = agg + d * (long long)CH;
    unsafeAtomicAdd(ad + lane,      xs[lane]);
    unsafeAtomicAdd(ad + lane + 64, xs[lane + 64]);
    if (lane == 0) unsafeAtomicAdd(cnt + d, 1.0f);
}

__global__ __launch_bounds__(256) void sage_out_kernel(
    const float* __restrict__ x, const float* agg, const float* __restrict__ cnt,
    const float* __restrict__ Wl, const float* __restrict__ Wr,
    const float* __restrict__ b, float* out, int n_nodes)
{
    __shared__ float s_mean[FB_NB][CH];
    __shared__ float s_x[FB_NB][CH];
    const int node0 = blockIdx.x * FB_NB;
    const int tid   = threadIdx.x;
    for (int i = tid; i < FB_NB * CH; i += 256) {
        int n = i >> 7, c = i & (CH - 1);
        int node = node0 + n;
        float a = 0.0f, xv = 0.0f, inv = 1.0f;
        if (node < n_nodes) {
            inv = 1.0f / fmaxf(cnt[node], 1.0f);
            a  = agg[(long long)node * CH + c];
            xv = x[(long long)node * CH + c];
        }
        s_mean[n][c] = a * inv;
        s_x[n][c]    = xv;
    }
    __syncthreads();
    const int cg = (tid & 31) * 4, nbase = (tid >> 5) * 2;
    float acc0[4] = {0,0,0,0}, acc1[4] = {0,0,0,0};
#pragma unroll 8
    for (int k = 0; k < CH; ++k) {
        float4 wl = *(const float4*)(Wl + k * CH + cg);
        float4 wr = *(const float4*)(Wr + k * CH + cg);
        float m0 = s_mean[nbase][k],   m1 = s_mean[nbase + 1][k];
        float x0 = s_x[nbase][k],      x1 = s_x[nbase + 1][k];
        acc0[0] += m0*wl.x + x0*wr.x;  acc0[1] += m0*wl.y + x0*wr.y;
        acc0[2] += m0*wl.z + x0*wr.z;  acc0[3] += m0*wl.w + x0*wr.w;
        acc1[0] += m1*wl.x + x1*wr.x;  acc1[1] += m1*wl.y + x1*wr.y;
        acc1[2] += m1*wl.z + x1*wr.z;  acc1[3] += m1*wl.w + x1*wr.w;
    }
    float4 bb = *(const float4*)(b + cg);
    int n0 = node0 + nbase, n1 = n0 + 1;
    if (n0 < n_nodes) {
        float4 o = { fmaxf(acc0[0]+bb.x,0.f), fmaxf(acc0[1]+bb.y,0.f),
                     fmaxf(acc0[2]+bb.z,0.f), fmaxf(acc0[3]+bb.w,0.f) };
        *(float4*)(out + (long long)n0 * CH + cg) = o;
    }
    if (n1 < n_nodes) {
        float4 o = { fmaxf(acc1[0]+bb.x,0.f), fmaxf(acc1[1]+bb.y,0.f),
                     fmaxf(acc1[2]+bb.z,0.f), fmaxf(acc1[3]+bb.w,0.f) };
        *(float4*)(out + (long long)n1 * CH + cg) = o;
    }
}

extern "C" void kernel_launch(void* const* d_in, const int* in_sizes, int n_in,
                              void* d_out, int out_size, void* d_ws, size_t ws_size,
                              hipStream_t stream)
{
    const float* x     = (const float*)d_in[0];
    const void*  edges = d_in[1];
    const float* Wl    = (const float*)d_in[2];
    const float* Wr    = (const float*)d_in[3];
    const float* b     = (const float*)d_in[4];
    float*       out   = (float*)d_out;

    const int n_nodes = in_sizes[0] / CH;
    const int n_edges = in_sizes[1] / 2;
    const long long n_x = (long long)n_nodes * CH;

    char* ws = (char*)d_ws;
    const size_t ints_n = (size_t)n_nodes * sizeof(int);
    const int    nscan  = (n_nodes + SC_T * SC_I - 1) / (SC_T * SC_I);
    const int    nbins  = (n_nodes + CSZ - 1) >> CSH;

    // tier-1 layout: offs(n+1) | bbase(513) | btot(512) | gcursor(512) | sorted | xb∪binned | Wt
    const size_t offs_b      = ((size_t)(n_nodes + 1) * sizeof(int) + 255) & ~(size_t)255;
    const size_t bbase_off   = offs_b;
    const size_t btot_off    = bbase_off + (NBMAX + 1) * sizeof(int);
    const size_t gcur_off    = btot_off + NBMAX * sizeof(int);
    const size_t sorted_off  = (gcur_off + NBMAX * sizeof(int) + 255) & ~(size_t)255;
    const size_t xb_off      = (sorted_off + (size_t)n_edges * sizeof(int) + 255) & ~(size_t)255;
    const size_t xb_bytes    = ((size_t)n_x * sizeof(ushort) > (size_t)n_edges * 4)
                             ? (size_t)n_x * sizeof(ushort) : (size_t)n_edges * 4;
    const size_t wt_off      = (xb_off + xb_bytes + 255) & ~(size_t)255;
    const size_t t1_need     = wt_off + (size_t)(CH * 2 * CH) * sizeof(ushort);

    // tier-3 layout (f32 path w/ legacy sort)
    const size_t t3_need = 3 * ints_n + 1024 * sizeof(int) + (size_t)n_edges * sizeof(int);

    if (ws_size >= t1_need && nbins <= NBMAX && n_nodes < (1 << 22)) {
        int*      offs    = (int*)ws;
        int*      bbase   = (int*)(ws + bbase_off);
        int*      btot    = (int*)(ws + btot_off);
        int*      gcursor = (int*)(ws + gcur_off);
        int*      sorted  = (int*)(ws + sorted_off);
        ushort*   xb      = (ushort*)(ws + xb_off);
        unsigned* binned  = (unsigned*)(ws + xb_off);   // aliases xb until sortfine2 done
        ushort*   Wt      = (ushort*)(ws + wt_off);

        hipMemsetAsync(btot, 0, NBMAX * sizeof(int), stream);

        const int hist_blocks = (n_edges + 256 * A1_E - 1) / (256 * A1_E);
        const long long cast_blocks = (n_x + 2047) / 2048;
        const int pb = (int)((cast_blocks > hist_blocks) ? cast_blocks : hist_blocks);

        const size_t binned_off  = (t1_need + 255) & ~(size_t)255;
        const size_t t1b_need    = binned_off + (size_t)n_edges * 4;
        if (ws_size >= t1b_need) {
            // binned has its own region: full fusion (hist+cast+wt in one pass).
            unsigned* binned2 = (unsigned*)(ws + binned_off);
            prep2_kernel<<<pb, 256, 0, stream>>>(edges, btot, n_edges, x, xb, n_x,
                                                 nbins, hist_blocks, Wl, Wr, Wt, 1);
            scanb_kernel<<<1, NBMAX, 0, stream>>>(btot, bbase, gcursor, offs,
                                                  nbins, n_edges, n_nodes);
            const int a1b = (n_edges + A1_T * A1_E - 1) / (A1_T * A1_E);
            bin_kernel<<<a1b, A1_T, 0, stream>>>(edges, gcursor, binned2, n_edges, nbins);
            sortfine2_kernel<<<nbins, CSZ, 0, stream>>>(binned2, bbase, offs, sorted, n_nodes);
        } else {
            // binned aliases xb: sort first, cast after.
            prep2_kernel<<<hist_blocks, 256, 0, stream>>>(edges, btot, n_edges,
                                                          x, xb, 0, nbins, hist_blocks,
                                                          Wl, Wr, Wt, 0);
            scanb_kernel<<<1, NBMAX, 0, stream>>>(btot, bbase, gcursor, offs,
                                                  nbins, n_edges, n_nodes);
            const int a1b = (n_edges + A1_T * A1_E - 1) / (A1_T * A1_E);
            bin_kernel<<<a1b, A1_T, 0, stream>>>(edges, gcursor, binned, n_edges, nbins);
            sortfine2_kernel<<<nbins, CSZ, 0, stream>>>(binned, bbase, offs, sorted, n_nodes);
            prep2_kernel<<<(int)cast_blocks, 256, 0, stream>>>(edges, btot, n_edges,
                                                               x, xb, n_x, nbins, 0,
                                                               Wl, Wr, Wt, 1);
        }

        const int ntiles = (n_nodes + NB - 1) / NB;
        fused_mfma_kernel<<<ntiles, 256, 0, stream>>>(
            xb, sorted, offs, Wt, b, out, n_nodes, n_edges);
    } else if (ws_size >= t3_need && nscan <= 1024) {
        int* deg    = (int*)ws;
        int* offs   = (int*)(ws + ints_n);
        int* cursor = (int*)(ws + 2 * ints_n);
        int* bsums  = (int*)(ws + 3 * ints_n);
        int* sorted = (int*)(ws + 3 * ints_n + 1024 * sizeof(int));

        hipMemsetAsync(deg, 0, ints_n, stream);
        const int eb = (n_edges + 255) / 256;
        hist_kernel<<<eb, 256, 0, stream>>>(edges, deg, n_edges);
        scan_blocks<<<nscan, SC_T, 0, stream>>>(deg, offs, bsums, n_nodes);
        fixup_kernel<<<(n_nodes + 255) / 256, 256, 0, stream>>>(offs, bsums, cursor, n_nodes);
        sort_kernel<<<eb, 256, 0, stream>>>(edges, cursor, sorted, n_edges);
        fused_kernel<<<(n_nodes + NB - 1) / NB, 256, 0, stream>>>(
            x, sorted, deg, offs, Wl, Wr, b, out, n_nodes);
    } else {
        float* agg = out;
        float* cnt = (float*)ws;
        hipMemsetAsync(agg, 0, (size_t)n_nodes * CH * sizeof(float), stream);
        hipMemsetAsync(cnt, 0, ints_n, stream);
        scatter_kernel<<<(n_edges + 3) / 4, 256, 0, stream>>>(x, edges, agg, cnt, n_edges);
        sage_out_kernel<<<(n_nodes + FB_NB - 1) / FB_NB, 256, 0, stream>>>(x, agg, cnt, Wl, Wr, b, out, n_nodes);
    }
}

// Round 11
// 159.647 us; speedup vs baseline: 2.1650x; 1.0162x over previous
//
#include <hip/hip_runtime.h>

#define CH 128
#define NB 64
#define LPAD 4
#define LSTR (NB + LPAD)
#define FB_NB 16
#define SC_T 256
#define SC_I 8
#define CSH 9
#define CSZ 512            // nodes per coarse bucket
#define NBMAX 512          // max coarse buckets (n_nodes <= 262144)
#define A1_T 1024
#define A1_E 8             // edges per thread in bin_kernel

typedef __attribute__((ext_vector_type(8))) __bf16 bf16x8;
typedef __attribute__((ext_vector_type(4))) float f32x4;

// ---------------------------------------------------------------------------
// bf16 helpers (RNE)
// ---------------------------------------------------------------------------
__device__ __forceinline__ unsigned bf16rne(float f) {
    unsigned u = __float_as_uint(f);
    return (u + 0x7FFFu + ((u >> 16) & 1u)) >> 16;
}
__device__ __forceinline__ unsigned pack2bf(float lo, float hi) {
    return bf16rne(lo) | (bf16rne(hi) << 16);
}

// int64-vs-int32 edge_index detection (odd words all zero => int64 < 2^31)
__device__ __forceinline__ int detect_f(const void* edges) {
    const int* ei = (const int*)edges;
    int hi_zero = (ei[1] == 0) & (ei[3] == 0) & (ei[5] == 0) & (ei[7] == 0);
    int lo_any  = (ei[0] | ei[2] | ei[4] | ei[6]) != 0;
    return hi_zero & lo_any;
}
__device__ __forceinline__ int load_dst(const void* edges, int e, int n_edges, int f) {
    const int* p = (const int*)edges;
    return f ? p[2 * (e + n_edges)] : p[e + n_edges];
}
__device__ __forceinline__ int load_src(const void* edges, int e, int f) {
    const int* p = (const int*)edges;
    return f ? p[2 * e] : p[e];
}

// ---------------------------------------------------------------------------
// prep2: coarse-bucket histogram (LDS, 512 bins) + x -> bf16 cast
//        + (optional) W transpose/cast fused into the first 128 blocks.
// ---------------------------------------------------------------------------
__global__ __launch_bounds__(256) void prep2_kernel(
    const void* __restrict__ edges, int* __restrict__ btot, int n_edges,
    const float* __restrict__ x, ushort* __restrict__ xb, long long n_x,
    int nbins, int hist_blocks,
    const float* __restrict__ Wl, const float* __restrict__ Wr,
    ushort* __restrict__ Wt, int do_wt)
{
    __shared__ int lh[NBMAX];
    const int blk = blockIdx.x, tid = threadIdx.x;
    if (blk < hist_blocks) {
        for (int i = tid; i < nbins; i += 256) lh[i] = 0;
        __syncthreads();
        const int f  = detect_f(edges);
        const int e0 = blk * (256 * A1_E) + tid;
#pragma unroll
        for (int j = 0; j < A1_E; ++j) {
            int e = e0 + j * 256;
            if (e < n_edges) atomicAdd(&lh[load_dst(edges, e, n_edges, f) >> CSH], 1);
        }
        __syncthreads();
        for (int i = tid; i < nbins; i += 256)
            if (lh[i]) atomicAdd(&btot[i], lh[i]);
    }
    long long i = (long long)blk * 256 + tid;
    long long base = i * 8;
    if (base + 8 <= n_x) {
        float4 a = *(const float4*)(x + base);
        float4 c = *(const float4*)(x + base + 4);
        uint4 o;
        o.x = pack2bf(a.x, a.y);
        o.y = pack2bf(a.z, a.w);
        o.z = pack2bf(c.x, c.y);
        o.w = pack2bf(c.z, c.w);
        *(uint4*)(xb + base) = o;
    } else {
        for (long long j = base; j < n_x; ++j) xb[j] = (ushort)bf16rne(x[j]);
    }
    if (do_wt) {
        int idx = blk * 256 + tid;
        if (idx < CH * 2 * CH) {
            int j = idx >> 8, k = idx & 255;
            float v = (k < CH) ? Wl[k * CH + j] : Wr[(k - CH) * CH + j];
            Wt[idx] = (ushort)bf16rne(v);
        }
    }
}

// ---------------------------------------------------------------------------
// bin edges into coarse buckets. Bucket bases computed in-LDS from btot scan
// (no separate scan kernel); cursor0 is zero-initialized.
// entry = src | (dst & 511) << 22   (requires n_nodes < 2^22)
// ---------------------------------------------------------------------------
__global__ __launch_bounds__(A1_T) void bin_kernel(
    const void* __restrict__ edges, const int* __restrict__ btot,
    int* __restrict__ cursor0, unsigned* __restrict__ binned,
    int n_edges, int nbins)
{
    __shared__ int lcnt[NBMAX];
    __shared__ int lbase[NBMAX];
    __shared__ int bb[NBMAX];
    const int f   = detect_f(edges);
    const int tid = threadIdx.x;

    int myv = 0;
    if (tid < NBMAX) {
        myv = (tid < nbins) ? btot[tid] : 0;
        bb[tid] = myv;
        lcnt[tid] = 0;
    }
    __syncthreads();
    for (int off = 1; off < NBMAX; off <<= 1) {
        int val = (tid < NBMAX && tid >= off) ? bb[tid - off] : 0;
        __syncthreads();
        if (tid < NBMAX) bb[tid] += val;
        __syncthreads();
    }

    int bin[A1_E], lrank[A1_E];
    unsigned ent[A1_E];
    const int e0 = blockIdx.x * (A1_T * A1_E);
#pragma unroll
    for (int j = 0; j < A1_E; ++j) {
        int e = e0 + j * A1_T + tid;
        bin[j] = -1;
        if (e < n_edges) {
            int s = load_src(edges, e, f);
            int d = load_dst(edges, e, n_edges, f);
            bin[j]   = d >> CSH;
            ent[j]   = (unsigned)s | ((unsigned)(d & (CSZ - 1)) << 22);
            lrank[j] = atomicAdd(&lcnt[bin[j]], 1);
        }
    }
    __syncthreads();
    if (tid < nbins) {
        int excl = bb[tid] - myv;
        lbase[tid] = excl + atomicAdd(&cursor0[tid], lcnt[tid]);
    }
    __syncthreads();
#pragma unroll
    for (int j = 0; j < A1_E; ++j)
        if (bin[j] >= 0) binned[lbase[bin[j]] + lrank[j]] = ent[j];
}

// ---------------------------------------------------------------------------
// per-bucket: in-LDS btot scan gives [start,end); LDS count -> scan ->
// write offs -> place into sorted. Writes stay in the block-exclusive window.
// ---------------------------------------------------------------------------
__global__ __launch_bounds__(CSZ) void sortfine2_kernel(
    const unsigned* __restrict__ binned, const int* __restrict__ btot,
    int* __restrict__ offs, int* __restrict__ sorted,
    int n_nodes, int n_edges, int nbins)
{
    __shared__ int cnt[CSZ];
    __shared__ int sc[CSZ];
    __shared__ int cur[CSZ];
    __shared__ int bb[NBMAX];
    const int c   = blockIdx.x;
    const int tid = threadIdx.x;

    int myv = (tid < nbins) ? btot[tid] : 0;
    bb[tid]  = myv;
    cnt[tid] = 0;
    __syncthreads();
    for (int off = 1; off < NBMAX; off <<= 1) {
        int val = (tid >= off) ? bb[tid - off] : 0;
        __syncthreads();
        bb[tid] += val;
        __syncthreads();
    }
    const int start = (c > 0) ? bb[c - 1] : 0;
    const int end   = bb[c];
    if (c == 0 && tid == 0) offs[n_nodes] = n_edges;

    for (int i = start + tid; i < end; i += CSZ)
        atomicAdd(&cnt[(binned[i] >> 22) & (CSZ - 1)], 1);
    __syncthreads();
    int v = cnt[tid];
    sc[tid] = v;
    __syncthreads();
    for (int off = 1; off < CSZ; off <<= 1) {
        int val = (tid >= off) ? sc[tid - off] : 0;
        __syncthreads();
        sc[tid] += val;
        __syncthreads();
    }
    int gpos = start + sc[tid] - v;        // global start of this node's range
    int node = (c << CSH) + tid;
    if (node < n_nodes) offs[node] = gpos;
    cur[tid] = gpos;
    __syncthreads();
    for (int i = start + tid; i < end; i += CSZ) {
        unsigned ent = binned[i];
        int r = atomicAdd(&cur[(ent >> 22) & (CSZ - 1)], 1);
        sorted[r] = (int)(ent & 0x3FFFFFu);
    }
}

// ---------------------------------------------------------------------------
// fused gather-mean + MFMA GEMM. One 64-node tile per block. LDS = s_m only
// (17.4 KB -> 8 blocks/CU); x A-fragments for MFMA ks>=4 read directly from
// global xb (block's 16KB x-tile, L1/L2-hot). Triple-buffered gather
// (named uA/uB/uC, rule #20). launch_bounds(256,4): VGPR cap 128, no spill
// (round-8 lesson: verify VGPR_Count~52-64 & WRITE_SIZE~50MB after bench).
// ---------------------------------------------------------------------------
__global__ __launch_bounds__(256, 4) void fused_mfma_kernel(
    const ushort* __restrict__ xb,
    const int* __restrict__ sorted,
    const int* __restrict__ offs,
    const ushort* __restrict__ Wt,
    const float* __restrict__ bias,
    float* __restrict__ out,
    int n_nodes, int nE)
{
    __shared__ ushort s_m[64][136];

    const int tid  = threadIdx.x;
    const int wave = tid >> 6;
    const int lane = tid & 63;
    const int rA   = lane & 15;
    const int gA   = lane >> 4;
    const int oc0  = wave * 32;
    const float b0 = bias[oc0 + rA];
    const float b1 = bias[oc0 + 16 + rA];

    const int node0 = blockIdx.x * NB;
    const int first = node0 + wave * 16;

    if (first < n_nodes) {
        const int nval = min(16, n_nodes - first);

        const int base0 = offs[first];
        const int e_end = offs[first + nval];
        const int Ew      = e_end - base0;
        const int nb_full = Ew >> 4;
        const int rem     = Ew & 15;

        int   nstored   = 0;
        int   cur_start = base0;
        int   cur_end   = offs[first + 1];
        float alo = 0.f, ahi = 0.f;

        int sv_cur = 0, sv_nxt = 0;
        if (Ew > 0) sv_cur = sorted[min(base0 + lane, nE - 1)];

        auto flushfn = [&](int ii) {
            while (ii == cur_end && nstored < nval) {
                float sc = 1.0f / fmaxf((float)(cur_end - cur_start), 1.0f);
                *(unsigned*)&s_m[wave * 16 + nstored][lane * 2] =
                    pack2bf(alo * sc, ahi * sc);
                alo = 0.f; ahi = 0.f;
                ++nstored;
                if (nstored < nval) {
                    cur_start = cur_end;
                    cur_end   = offs[first + nstored + 1];
                }
            }
        };
        auto issue = [&](unsigned (&U)[16], int bb) {
            if ((bb & 3) == 0) {
                if (bb > 0) sv_cur = sv_nxt;
                int c = (bb >> 2) + 1;
                if (c * 64 < Ew) sv_nxt = sorted[min(base0 + c * 64 + lane, nE - 1)];
            }
            int q = (bb & 3) * 16;
#pragma unroll
            for (int t = 0; t < 16; ++t) {
                int s = __shfl(sv_cur, q + t);
                U[t] = *(const unsigned*)(xb + (size_t)s * CH + lane * 2);
            }
        };
        auto accum = [&](unsigned (&U)[16], int bb) {
            int i0 = base0 + bb * 16;
#pragma unroll
            for (int t = 0; t < 16; ++t) {
                flushfn(i0 + t);
                alo += __uint_as_float(U[t] << 16);
                ahi += __uint_as_float(U[t] & 0xFFFF0000u);
            }
        };

        // 3-deep software pipeline: issue runs 2 batches ahead of accum.
        unsigned uA[16], uB[16], uC[16];
        if (nb_full > 0) issue(uA, 0);
        if (nb_full > 1) issue(uB, 1);
        int bI = 0;
        while (bI < nb_full) {
            if (bI + 2 < nb_full) issue(uC, bI + 2);
            accum(uA, bI);
            ++bI; if (bI >= nb_full) break;
            if (bI + 2 < nb_full) issue(uA, bI + 2);
            accum(uB, bI);
            ++bI; if (bI >= nb_full) break;
            if (bI + 2 < nb_full) issue(uB, bI + 2);
            accum(uC, bI);
            ++bI;
        }

        if (rem > 0) {
            if (nb_full > 0 && (nb_full & 3) == 0) sv_cur = sv_nxt;
            int q = (nb_full & 3) * 16;
            for (int t = 0; t < rem; ++t) {
                int i = base0 + nb_full * 16 + t;
                int s = __shfl(sv_cur, q + t);
                unsigned u = *(const unsigned*)(xb + (size_t)s * CH + lane * 2);
                flushfn(i);
                alo += __uint_as_float(u << 16);
                ahi += __uint_as_float(u & 0xFFFF0000u);
            }
        }
        while (nstored < nval) {
            float sc = 1.0f / fmaxf((float)(cur_end - cur_start), 1.0f);
            *(unsigned*)&s_m[wave * 16 + nstored][lane * 2] =
                pack2bf(alo * sc, ahi * sc);
            alo = 0.f; ahi = 0.f;
            ++nstored;
            if (nstored < nval) {
                cur_start = cur_end;
                cur_end   = offs[first + nstored + 1];
            }
        }
    }
    __syncthreads();

    f32x4 acc[4][2];
#pragma unroll
    for (int nt = 0; nt < 4; ++nt) {
        acc[nt][0] = (f32x4){0.f, 0.f, 0.f, 0.f};
        acc[nt][1] = (f32x4){0.f, 0.f, 0.f, 0.f};
    }

#pragma unroll
    for (int ks = 0; ks < 8; ++ks) {
        const int kk = (ks & 3) * 32 + gA * 8;
        const ushort* wrow = Wt + ks * 32 + gA * 8;
        bf16x8 bf0 = __builtin_bit_cast(bf16x8,
            *(const uint4*)(wrow + (oc0 + rA) * 256));
        bf16x8 bf1 = __builtin_bit_cast(bf16x8,
            *(const uint4*)(wrow + (oc0 + 16 + rA) * 256));
#pragma unroll
        for (int nt = 0; nt < 4; ++nt) {
            bf16x8 af;
            if (ks < 4) {
                af = __builtin_bit_cast(bf16x8,
                    *(const uint4*)&s_m[nt * 16 + rA][kk]);
            } else {
                int row = node0 + nt * 16 + rA;
                row = (row < n_nodes) ? row : (n_nodes - 1);
                af = __builtin_bit_cast(bf16x8,
                    *(const uint4*)(xb + (size_t)row * CH + kk));
            }
            acc[nt][0] = __builtin_amdgcn_mfma_f32_16x16x32_bf16(af, bf0, acc[nt][0], 0, 0, 0);
            acc[nt][1] = __builtin_amdgcn_mfma_f32_16x16x32_bf16(af, bf1, acc[nt][1], 0, 0, 0);
        }
    }

#pragma unroll
    for (int nt = 0; nt < 4; ++nt) {
        int nbase = node0 + nt * 16 + gA * 4;
#pragma unroll
        for (int r = 0; r < 4; ++r) {
            int node = nbase + r;
            if (node < n_nodes) {
                out[(size_t)node * CH + oc0 + rA]      = fmaxf(acc[nt][0][r] + b0, 0.f);
                out[(size_t)node * CH + oc0 + 16 + rA] = fmaxf(acc[nt][1][r] + b1, 0.f);
            }
        }
    }
}

// ---------------------------------------------------------------------------
// legacy helpers for fallback tiers
// ---------------------------------------------------------------------------
__global__ __launch_bounds__(256) void hist_kernel(
    const void* __restrict__ edges, int* __restrict__ deg, int n_edges)
{
    const int f = detect_f(edges);
    int e = blockIdx.x * 256 + threadIdx.x;
    if (e >= n_edges) return;
    atomicAdd(&deg[load_dst(edges, e, n_edges, f)], 1);
}

__global__ __launch_bounds__(SC_T) void scan_blocks(
    const int* __restrict__ deg, int* __restrict__ offs,
    int* __restrict__ bsums, int n)
{
    __shared__ int s_sum[SC_T];
    const int t = threadIdx.x;
    const int base = blockIdx.x * SC_T * SC_I + t * SC_I;
    int v[SC_I];
    int tsum = 0;
#pragma unroll
    for (int i = 0; i < SC_I; ++i) {
        int idx = base + i;
        v[i] = (idx < n) ? deg[idx] : 0;
        tsum += v[i];
    }
    s_sum[t] = tsum;
    __syncthreads();
    for (int off = 1; off < SC_T; off <<= 1) {
        int val = (t >= off) ? s_sum[t - off] : 0;
        __syncthreads();
        s_sum[t] += val;
        __syncthreads();
    }
    int run = s_sum[t] - tsum;
#pragma unroll
    for (int i = 0; i < SC_I; ++i) {
        int idx = base + i;
        if (idx < n) offs[idx] = run;
        run += v[i];
    }
    if (t == SC_T - 1) bsums[blockIdx.x] = s_sum[t];
}

__global__ __launch_bounds__(256) void fixup_kernel(
    int* __restrict__ offs, const int* __restrict__ bsums,
    int* __restrict__ cursor, int n)
{
    int i = blockIdx.x * 256 + threadIdx.x;
    if (i >= n) return;
    int bucket = i / (SC_T * SC_I);
    int add = 0;
    for (int j = 0; j < bucket; ++j) add += bsums[j];
    int o = offs[i] + add;
    offs[i] = o;
    cursor[i] = o;
}

__global__ __launch_bounds__(256) void sort_kernel(
    const void* __restrict__ edges,
    int* __restrict__ cursor, int* __restrict__ sorted, int n_edges)
{
    const int f = detect_f(edges);
    int e = blockIdx.x * 256 + threadIdx.x;
    if (e >= n_edges) return;
    int d = load_dst(edges, e, n_edges, f);
    int s = load_src(edges, e, f);
    int pos = atomicAdd(&cursor[d], 1);
    sorted[pos] = s;
}

__global__ __launch_bounds__(256) void fused_kernel(
    const float* __restrict__ x,
    const int* __restrict__ sorted,
    const int* __restrict__ deg,
    const int* __restrict__ offs,
    const float* __restrict__ Wl,
    const float* __restrict__ Wr,
    const float* __restrict__ b,
    float* __restrict__ out,
    int n_nodes)
{
    __shared__ float s_m[CH][LSTR];
    __shared__ float s_v[CH][LSTR];

    const int node0 = blockIdx.x * NB;
    const int tid   = threadIdx.x;
    const int wave  = tid >> 6;
    const int lane  = tid & 63;

    for (int nn = 0; nn < 16; ++nn) {
        int n    = wave * 16 + nn;
        int node = node0 + n;
        float a0 = 0.f, a1 = 0.f, x0 = 0.f, x1 = 0.f;
        if (node < n_nodes) {
            const float* xr = x + (long long)node * CH;
            x0 = xr[lane];
            x1 = xr[lane + 64];
            int base = offs[node];
            int dg   = deg[node];
            for (int j0 = 0; j0 < dg; j0 += 64) {
                int m  = min(64, dg - j0);
                int sv = (j0 + lane < dg) ? sorted[base + j0 + lane] : 0;
                int jj = 0;
                for (; jj + 8 <= m; jj += 8) {
                    float v0[8], v1[8];
#pragma unroll
                    for (int u = 0; u < 8; ++u) {
                        int s = __shfl(sv, jj + u);
                        const float* p = x + (long long)s * CH;
                        v0[u] = p[lane];
                        v1[u] = p[lane + 64];
                    }
#pragma unroll
                    for (int u = 0; u < 8; ++u) { a0 += v0[u]; a1 += v1[u]; }
                }
                for (; jj < m; ++jj) {
                    int s = __shfl(sv, jj);
                    const float* p = x + (long long)s * CH;
                    a0 += p[lane];
                    a1 += p[lane + 64];
                }
            }
            float inv = 1.0f / fmaxf((float)dg, 1.0f);
            a0 *= inv; a1 *= inv;
        }
        s_m[lane][n]      = a0;
        s_m[lane + 64][n] = a1;
        s_v[lane][n]      = x0;
        s_v[lane + 64][n] = x1;
    }
    __syncthreads();

    const int cg = (tid & 31) * 4;
    const int ng = (tid >> 5) * 8;

    float acc[8][4];
#pragma unroll
    for (int u = 0; u < 8; ++u)
#pragma unroll
        for (int j = 0; j < 4; ++j) acc[u][j] = 0.f;

#pragma unroll 4
    for (int k = 0; k < CH; ++k) {
        const float* mr = &s_m[k][ng];
        const float* vr = &s_v[k][ng];
        float4 wl = *(const float4*)(Wl + k * CH + cg);
        float4 wr = *(const float4*)(Wr + k * CH + cg);
#pragma unroll
        for (int u = 0; u < 8; ++u) {
            float m  = mr[u];
            float xv = vr[u];
            acc[u][0] += m * wl.x + xv * wr.x;
            acc[u][1] += m * wl.y + xv * wr.y;
            acc[u][2] += m * wl.z + xv * wr.z;
            acc[u][3] += m * wl.w + xv * wr.w;
        }
    }

    float4 bb = *(const float4*)(b + cg);
#pragma unroll
    for (int u = 0; u < 8; ++u) {
        int node = node0 + ng + u;
        if (node < n_nodes) {
            float4 o;
            o.x = fmaxf(acc[u][0] + bb.x, 0.0f);
            o.y = fmaxf(acc[u][1] + bb.y, 0.0f);
            o.z = fmaxf(acc[u][2] + bb.z, 0.0f);
            o.w = fmaxf(acc[u][3] + bb.w, 0.0f);
            *(float4*)(out + (long long)node * CH + cg) = o;
        }
    }
}

__global__ __launch_bounds__(256) void scatter_kernel(
    const float* __restrict__ x, const void* __restrict__ edges,
    float* __restrict__ agg, float* __restrict__ cnt, int n_edges)
{
    const int f = detect_f(edges);
    int e = blockIdx.x * 4 + (threadIdx.x >> 6);
    if (e >= n_edges) return;
    int lane = threadIdx.x & 63;
    long long s = load_src(edges, e, f);
    long long d = load_dst(edges, e, n_edges, f);
    const float* xs = x + s * (long long)CH;
    float*       ad = agg + d * (long long)CH;
    unsafeAtomicAdd(ad + lane,      xs[lane]);
    unsafeAtomicAdd(ad + lane + 64, xs[lane + 64]);
    if (lane == 0) unsafeAtomicAdd(cnt + d, 1.0f);
}

__global__ __launch_bounds__(256) void sage_out_kernel(
    const float* __restrict__ x, const float* agg, const float* __restrict__ cnt,
    const float* __restrict__ Wl, const float* __restrict__ Wr,
    const float* __restrict__ b, float* out, int n_nodes)
{
    __shared__ float s_mean[FB_NB][CH];
    __shared__ float s_x[FB_NB][CH];
    const int node0 = blockIdx.x * FB_NB;
    const int tid   = threadIdx.x;
    for (int i = tid; i < FB_NB * CH; i += 256) {
        int n = i >> 7, c = i & (CH - 1);
        int node = node0 + n;
        float a = 0.0f, xv = 0.0f, inv = 1.0f;
        if (node < n_nodes) {
            inv = 1.0f / fmaxf(cnt[node], 1.0f);
            a  = agg[(long long)node * CH + c];
            xv = x[(long long)node * CH + c];
        }
        s_mean[n][c] = a * inv;
        s_x[n][c]    = xv;
    }
    __syncthreads();
    const int cg = (tid & 31) * 4, nbase = (tid >> 5) * 2;
    float acc0[4] = {0,0,0,0}, acc1[4] = {0,0,0,0};
#pragma unroll 8
    for (int k = 0; k < CH; ++k) {
        float4 wl = *(const float4*)(Wl + k * CH + cg);
        float4 wr = *(const float4*)(Wr + k * CH + cg);
        float m0 = s_mean[nbase][k],   m1 = s_mean[nbase + 1][k];
        float x0 = s_x[nbase][k],      x1 = s_x[nbase + 1][k];
        acc0[0] += m0*wl.x + x0*wr.x;  acc0[1] += m0*wl.y + x0*wr.y;
        acc0[2] += m0*wl.z + x0*wr.z;  acc0[3] += m0*wl.w + x0*wr.w;
        acc1[0] += m1*wl.x + x1*wr.x;  acc1[1] += m1*wl.y + x1*wr.y;
        acc1[2] += m1*wl.z + x1*wr.z;  acc1[3] += m1*wl.w + x1*wr.w;
    }
    float4 bb = *(const float4*)(b + cg);
    int n0 = node0 + nbase, n1 = n0 + 1;
    if (n0 < n_nodes) {
        float4 o = { fmaxf(acc0[0]+bb.x,0.f), fmaxf(acc0[1]+bb.y,0.f),
                     fmaxf(acc0[2]+bb.z,0.f), fmaxf(acc0[3]+bb.w,0.f) };
        *(float4*)(out + (long long)n0 * CH + cg) = o;
    }
    if (n1 < n_nodes) {
        float4 o = { fmaxf(acc1[0]+bb.x,0.f), fmaxf(acc1[1]+bb.y,0.f),
                     fmaxf(acc1[2]+bb.z,0.f), fmaxf(acc1[3]+bb.w,0.f) };
        *(float4*)(out + (long long)n1 * CH + cg) = o;
    }
}

extern "C" void kernel_launch(void* const* d_in, const int* in_sizes, int n_in,
                              void* d_out, int out_size, void* d_ws, size_t ws_size,
                              hipStream_t stream)
{
    const float* x     = (const float*)d_in[0];
    const void*  edges = d_in[1];
    const float* Wl    = (const float*)d_in[2];
    const float* Wr    = (const float*)d_in[3];
    const float* b     = (const float*)d_in[4];
    float*       out   = (float*)d_out;

    const int n_nodes = in_sizes[0] / CH;
    const int n_edges = in_sizes[1] / 2;
    const long long n_x = (long long)n_nodes * CH;

    char* ws = (char*)d_ws;
    const size_t ints_n = (size_t)n_nodes * sizeof(int);
    const int    nscan  = (n_nodes + SC_T * SC_I - 1) / (SC_T * SC_I);
    const int    nbins  = (n_nodes + CSZ - 1) >> CSH;

    // tier-1 layout: offs(n+1) | btot(512) | cursor0(512) | sorted | xb∪binned | Wt
    const size_t offs_b      = ((size_t)(n_nodes + 1) * sizeof(int) + 255) & ~(size_t)255;
    const size_t btot_off    = offs_b;
    const size_t gcur_off    = btot_off + NBMAX * sizeof(int);
    const size_t sorted_off  = (gcur_off + NBMAX * sizeof(int) + 255) & ~(size_t)255;
    const size_t xb_off      = (sorted_off + (size_t)n_edges * sizeof(int) + 255) & ~(size_t)255;
    const size_t xb_bytes    = ((size_t)n_x * sizeof(ushort) > (size_t)n_edges * 4)
                             ? (size_t)n_x * sizeof(ushort) : (size_t)n_edges * 4;
    const size_t wt_off      = (xb_off + xb_bytes + 255) & ~(size_t)255;
    const size_t t1_need     = wt_off + (size_t)(CH * 2 * CH) * sizeof(ushort);

    // tier-3 layout (f32 path w/ legacy sort)
    const size_t t3_need = 3 * ints_n + 1024 * sizeof(int) + (size_t)n_edges * sizeof(int);

    if (ws_size >= t1_need && nbins <= NBMAX && n_nodes < (1 << 22)) {
        int*      offs    = (int*)ws;
        int*      btot    = (int*)(ws + btot_off);
        int*      cursor0 = (int*)(ws + gcur_off);
        int*      sorted  = (int*)(ws + sorted_off);
        ushort*   xb      = (ushort*)(ws + xb_off);
        unsigned* binned  = (unsigned*)(ws + xb_off);   // aliases xb until sortfine2 done
        ushort*   Wt      = (ushort*)(ws + wt_off);

        // zero btot + cursor0 in one shot (adjacent)
        hipMemsetAsync(btot, 0, 2 * NBMAX * sizeof(int), stream);

        const int hist_blocks = (n_edges + 256 * A1_E - 1) / (256 * A1_E);
        const long long cast_blocks = (n_x + 2047) / 2048;
        const int pb = (int)((cast_blocks > hist_blocks) ? cast_blocks : hist_blocks);
        const int a1b = (n_edges + A1_T * A1_E - 1) / (A1_T * A1_E);

        const size_t binned_off  = (t1_need + 255) & ~(size_t)255;
        const size_t t1b_need    = binned_off + (size_t)n_edges * 4;
        if (ws_size >= t1b_need) {
            // binned has its own region: full fusion (hist+cast+wt in one pass).
            unsigned* binned2 = (unsigned*)(ws + binned_off);
            prep2_kernel<<<pb, 256, 0, stream>>>(edges, btot, n_edges, x, xb, n_x,
                                                 nbins, hist_blocks, Wl, Wr, Wt, 1);
            bin_kernel<<<a1b, A1_T, 0, stream>>>(edges, btot, cursor0, binned2,
                                                 n_edges, nbins);
            sortfine2_kernel<<<nbins, CSZ, 0, stream>>>(binned2, btot, offs, sorted,
                                                        n_nodes, n_edges, nbins);
        } else {
            // binned aliases xb: sort first, cast after.
            prep2_kernel<<<hist_blocks, 256, 0, stream>>>(edges, btot, n_edges,
                                                          x, xb, 0, nbins, hist_blocks,
                                                          Wl, Wr, Wt, 0);
            bin_kernel<<<a1b, A1_T, 0, stream>>>(edges, btot, cursor0, binned,
                                                 n_edges, nbins);
            sortfine2_kernel<<<nbins, CSZ, 0, stream>>>(binned, btot, offs, sorted,
                                                        n_nodes, n_edges, nbins);
            prep2_kernel<<<(int)cast_blocks, 256, 0, stream>>>(edges, btot, n_edges,
                                                               x, xb, n_x, nbins, 0,
                                                               Wl, Wr, Wt, 1);
        }

        const int ntiles = (n_nodes + NB - 1) / NB;
        fused_mfma_kernel<<<ntiles, 256, 0, stream>>>(
            xb, sorted, offs, Wt, b, out, n_nodes, n_edges);
    } else if (ws_size >= t3_need && nscan <= 1024) {
        int* deg    = (int*)ws;
        int* offs   = (int*)(ws + ints_n);
        int* cursor = (int*)(ws + 2 * ints_n);
        int* bsums  = (int*)(ws + 3 * ints_n);
        int* sorted = (int*)(ws + 3 * ints_n + 1024 * sizeof(int));

        hipMemsetAsync(deg, 0, ints_n, stream);
        const int eb = (n_edges + 255) / 256;
        hist_kernel<<<eb, 256, 0, stream>>>(edges, deg, n_edges);
        scan_blocks<<<nscan, SC_T, 0, stream>>>(deg, offs, bsums, n_nodes);
        fixup_kernel<<<(n_nodes + 255) / 256, 256, 0, stream>>>(offs, bsums, cursor, n_nodes);
        sort_kernel<<<eb, 256, 0, stream>>>(edges, cursor, sorted, n_edges);
        fused_kernel<<<(n_nodes + NB - 1) / NB, 256, 0, stream>>>(
            x, sorted, deg, offs, Wl, Wr, b, out, n_nodes);
    } else {
        float* agg = out;
        float* cnt = (float*)ws;
        hipMemsetAsync(agg, 0, (size_t)n_nodes * CH * sizeof(float), stream);
        hipMemsetAsync(cnt, 0, ints_n, stream);
        scatter_kernel<<<(n_edges + 3) / 4, 256, 0, stream>>>(x, edges, agg, cnt, n_edges);
        sage_out_kernel<<<(n_nodes + FB_NB - 1) / FB_NB, 256, 0, stream>>>(x, agg, cnt, Wl, Wr, b, out, n_nodes);
    }
}

// Round 12
// 149.619 us; speedup vs baseline: 2.3101x; 1.0670x over previous
//
#include <hip/hip_runtime.h>

#define CH 128
#define NB 64
#define LPAD 4
#define LSTR (NB + LPAD)
#define FB_NB 16
#define SC_T 256
#define SC_I 8
#define CSH 9
#define CSZ 512            // nodes per coarse bucket
#define NBMAX 512          // max coarse buckets (n_nodes <= 262144)
#define A1_T 1024
#define A1_E 8             // edges per thread in bin_kernel

typedef __attribute__((ext_vector_type(8))) __bf16 bf16x8;
typedef __attribute__((ext_vector_type(4))) float f32x4;

// ---------------------------------------------------------------------------
// bf16 helpers (RNE)
// ---------------------------------------------------------------------------
__device__ __forceinline__ unsigned bf16rne(float f) {
    unsigned u = __float_as_uint(f);
    return (u + 0x7FFFu + ((u >> 16) & 1u)) >> 16;
}
__device__ __forceinline__ unsigned pack2bf(float lo, float hi) {
    return bf16rne(lo) | (bf16rne(hi) << 16);
}

// int64-vs-int32 edge_index detection (odd words all zero => int64 < 2^31)
__device__ __forceinline__ int detect_f(const void* edges) {
    const int* ei = (const int*)edges;
    int hi_zero = (ei[1] == 0) & (ei[3] == 0) & (ei[5] == 0) & (ei[7] == 0);
    int lo_any  = (ei[0] | ei[2] | ei[4] | ei[6]) != 0;
    return hi_zero & lo_any;
}
__device__ __forceinline__ int load_dst(const void* edges, int e, int n_edges, int f) {
    const int* p = (const int*)edges;
    return f ? p[2 * (e + n_edges)] : p[e + n_edges];
}
__device__ __forceinline__ int load_src(const void* edges, int e, int f) {
    const int* p = (const int*)edges;
    return f ? p[2 * e] : p[e];
}

// ---------------------------------------------------------------------------
// prep2: coarse-bucket histogram (LDS, 512 bins) + x -> bf16 cast
//        + W transpose/cast fused into the first 128 blocks.
// ---------------------------------------------------------------------------
__global__ __launch_bounds__(256) void prep2_kernel(
    const void* __restrict__ edges, int* __restrict__ btot, int n_edges,
    const float* __restrict__ x, ushort* __restrict__ xb, long long n_x,
    int nbins, int hist_blocks,
    const float* __restrict__ Wl, const float* __restrict__ Wr,
    ushort* __restrict__ Wt, int do_wt)
{
    __shared__ int lh[NBMAX];
    const int blk = blockIdx.x, tid = threadIdx.x;
    if (blk < hist_blocks) {
        for (int i = tid; i < nbins; i += 256) lh[i] = 0;
        __syncthreads();
        const int f  = detect_f(edges);
        const int e0 = blk * (256 * A1_E) + tid;
#pragma unroll
        for (int j = 0; j < A1_E; ++j) {
            int e = e0 + j * 256;
            if (e < n_edges) atomicAdd(&lh[load_dst(edges, e, n_edges, f) >> CSH], 1);
        }
        __syncthreads();
        for (int i = tid; i < nbins; i += 256)
            if (lh[i]) atomicAdd(&btot[i], lh[i]);
    }
    long long i = (long long)blk * 256 + tid;
    long long base = i * 8;
    if (base + 8 <= n_x) {
        float4 a = *(const float4*)(x + base);
        float4 c = *(const float4*)(x + base + 4);
        uint4 o;
        o.x = pack2bf(a.x, a.y);
        o.y = pack2bf(a.z, a.w);
        o.z = pack2bf(c.x, c.y);
        o.w = pack2bf(c.z, c.w);
        *(uint4*)(xb + base) = o;
    } else {
        for (long long j = base; j < n_x; ++j) xb[j] = (ushort)bf16rne(x[j]);
    }
    if (do_wt) {
        int idx = blk * 256 + tid;
        if (idx < CH * 2 * CH) {
            int j = idx >> 8, k = idx & 255;
            float v = (k < CH) ? Wl[k * CH + j] : Wr[(k - CH) * CH + j];
            Wt[idx] = (ushort)bf16rne(v);
        }
    }
}

// ---------------------------------------------------------------------------
// bin edges into coarse buckets. Bucket bases computed in-LDS from btot scan
// (no separate scan kernel); cursor0 is zero-initialized.
// entry = src | (dst & 511) << 22   (requires n_nodes < 2^22)
// ---------------------------------------------------------------------------
__global__ __launch_bounds__(A1_T) void bin_kernel(
    const void* __restrict__ edges, const int* __restrict__ btot,
    int* __restrict__ cursor0, unsigned* __restrict__ binned,
    int n_edges, int nbins)
{
    __shared__ int lcnt[NBMAX];
    __shared__ int lbase[NBMAX];
    __shared__ int bb[NBMAX];
    const int f   = detect_f(edges);
    const int tid = threadIdx.x;

    int myv = 0;
    if (tid < NBMAX) {
        myv = (tid < nbins) ? btot[tid] : 0;
        bb[tid] = myv;
        lcnt[tid] = 0;
    }
    __syncthreads();
    for (int off = 1; off < NBMAX; off <<= 1) {
        int val = (tid < NBMAX && tid >= off) ? bb[tid - off] : 0;
        __syncthreads();
        if (tid < NBMAX) bb[tid] += val;
        __syncthreads();
    }

    int bin[A1_E], lrank[A1_E];
    unsigned ent[A1_E];
    const int e0 = blockIdx.x * (A1_T * A1_E);
#pragma unroll
    for (int j = 0; j < A1_E; ++j) {
        int e = e0 + j * A1_T + tid;
        bin[j] = -1;
        if (e < n_edges) {
            int s = load_src(edges, e, f);
            int d = load_dst(edges, e, n_edges, f);
            bin[j]   = d >> CSH;
            ent[j]   = (unsigned)s | ((unsigned)(d & (CSZ - 1)) << 22);
            lrank[j] = atomicAdd(&lcnt[bin[j]], 1);
        }
    }
    __syncthreads();
    if (tid < nbins) {
        int excl = bb[tid] - myv;
        lbase[tid] = excl + atomicAdd(&cursor0[tid], lcnt[tid]);
    }
    __syncthreads();
#pragma unroll
    for (int j = 0; j < A1_E; ++j)
        if (bin[j] >= 0) binned[lbase[bin[j]] + lrank[j]] = ent[j];
}

// ---------------------------------------------------------------------------
// per-bucket: in-LDS btot scan gives [start,end); LDS count -> scan ->
// write offs -> place into sorted. Writes stay in the block-exclusive window.
// ---------------------------------------------------------------------------
__global__ __launch_bounds__(CSZ) void sortfine2_kernel(
    const unsigned* __restrict__ binned, const int* __restrict__ btot,
    int* __restrict__ offs, int* __restrict__ sorted,
    int n_nodes, int n_edges, int nbins)
{
    __shared__ int cnt[CSZ];
    __shared__ int sc[CSZ];
    __shared__ int cur[CSZ];
    __shared__ int bb[NBMAX];
    const int c   = blockIdx.x;
    const int tid = threadIdx.x;

    int myv = (tid < nbins) ? btot[tid] : 0;
    bb[tid]  = myv;
    cnt[tid] = 0;
    __syncthreads();
    for (int off = 1; off < NBMAX; off <<= 1) {
        int val = (tid >= off) ? bb[tid - off] : 0;
        __syncthreads();
        bb[tid] += val;
        __syncthreads();
    }
    const int start = (c > 0) ? bb[c - 1] : 0;
    const int end   = bb[c];
    if (c == 0 && tid == 0) offs[n_nodes] = n_edges;

    for (int i = start + tid; i < end; i += CSZ)
        atomicAdd(&cnt[(binned[i] >> 22) & (CSZ - 1)], 1);
    __syncthreads();
    int v = cnt[tid];
    sc[tid] = v;
    __syncthreads();
    for (int off = 1; off < CSZ; off <<= 1) {
        int val = (tid >= off) ? sc[tid - off] : 0;
        __syncthreads();
        sc[tid] += val;
        __syncthreads();
    }
    int gpos = start + sc[tid] - v;        // global start of this node's range
    int node = (c << CSH) + tid;
    if (node < n_nodes) offs[node] = gpos;
    cur[tid] = gpos;
    __syncthreads();
    for (int i = start + tid; i < end; i += CSZ) {
        unsigned ent = binned[i];
        int r = atomicAdd(&cur[(ent >> 22) & (CSZ - 1)], 1);
        sorted[r] = (int)(ent & 0x3FFFFFu);
    }
}

// ---------------------------------------------------------------------------
// fused gather-mean + MFMA GEMM (round-10 proven config: s_m + s_v LDS
// staging, 34.8 KB, launch_bounds(256,4), triple-buffered gather with named
// uA/uB/uC, non-persistent grid, degree from offs diffs). Measured 92.6 us.
// ---------------------------------------------------------------------------
__global__ __launch_bounds__(256, 4) void fused_mfma_kernel(
    const ushort* __restrict__ xb,
    const int* __restrict__ sorted,
    const int* __restrict__ offs,
    const ushort* __restrict__ Wt,
    const float* __restrict__ bias,
    float* __restrict__ out,
    int n_nodes, int nE)
{
    __shared__ ushort s_m[64][136];
    __shared__ ushort s_v[64][136];

    const int tid  = threadIdx.x;
    const int wave = tid >> 6;
    const int lane = tid & 63;
    const int rA   = lane & 15;
    const int gA   = lane >> 4;
    const int oc0  = wave * 32;
    const float b0 = bias[oc0 + rA];
    const float b1 = bias[oc0 + 16 + rA];

    const int node0 = blockIdx.x * NB;
    const int first = node0 + wave * 16;

    if (first < n_nodes) {
        const int nval = min(16, n_nodes - first);

#pragma unroll
        for (int nn = 0; nn < 16; ++nn) {
            int node = min(first + nn, n_nodes - 1);
            unsigned u = *(const unsigned*)(xb + (size_t)node * CH + lane * 2);
            *(unsigned*)&s_v[wave * 16 + nn][lane * 2] = u;
        }

        const int base0 = offs[first];
        const int e_end = offs[first + nval];
        const int Ew      = e_end - base0;
        const int nb_full = Ew >> 4;
        const int rem     = Ew & 15;

        int   nstored   = 0;
        int   cur_start = base0;
        int   cur_end   = offs[first + 1];
        float alo = 0.f, ahi = 0.f;

        int sv_cur = 0, sv_nxt = 0;
        if (Ew > 0) sv_cur = sorted[min(base0 + lane, nE - 1)];

        auto flushfn = [&](int ii) {
            while (ii == cur_end && nstored < nval) {
                float sc = 1.0f / fmaxf((float)(cur_end - cur_start), 1.0f);
                *(unsigned*)&s_m[wave * 16 + nstored][lane * 2] =
                    pack2bf(alo * sc, ahi * sc);
                alo = 0.f; ahi = 0.f;
                ++nstored;
                if (nstored < nval) {
                    cur_start = cur_end;
                    cur_end   = offs[first + nstored + 1];
                }
            }
        };
        auto issue = [&](unsigned (&U)[16], int bb) {
            if ((bb & 3) == 0) {
                if (bb > 0) sv_cur = sv_nxt;
                int c = (bb >> 2) + 1;
                if (c * 64 < Ew) sv_nxt = sorted[min(base0 + c * 64 + lane, nE - 1)];
            }
            int q = (bb & 3) * 16;
#pragma unroll
            for (int t = 0; t < 16; ++t) {
                int s = __shfl(sv_cur, q + t);
                U[t] = *(const unsigned*)(xb + (size_t)s * CH + lane * 2);
            }
        };
        auto accum = [&](unsigned (&U)[16], int bb) {
            int i0 = base0 + bb * 16;
#pragma unroll
            for (int t = 0; t < 16; ++t) {
                flushfn(i0 + t);
                alo += __uint_as_float(U[t] << 16);
                ahi += __uint_as_float(U[t] & 0xFFFF0000u);
            }
        };

        // 3-deep software pipeline: issue runs 2 batches ahead of accum.
        unsigned uA[16], uB[16], uC[16];
        if (nb_full > 0) issue(uA, 0);
        if (nb_full > 1) issue(uB, 1);
        int bI = 0;
        while (bI < nb_full) {
            if (bI + 2 < nb_full) issue(uC, bI + 2);
            accum(uA, bI);
            ++bI; if (bI >= nb_full) break;
            if (bI + 2 < nb_full) issue(uA, bI + 2);
            accum(uB, bI);
            ++bI; if (bI >= nb_full) break;
            if (bI + 2 < nb_full) issue(uB, bI + 2);
            accum(uC, bI);
            ++bI;
        }

        if (rem > 0) {
            if (nb_full > 0 && (nb_full & 3) == 0) sv_cur = sv_nxt;
            int q = (nb_full & 3) * 16;
            for (int t = 0; t < rem; ++t) {
                int i = base0 + nb_full * 16 + t;
                int s = __shfl(sv_cur, q + t);
                unsigned u = *(const unsigned*)(xb + (size_t)s * CH + lane * 2);
                flushfn(i);
                alo += __uint_as_float(u << 16);
                ahi += __uint_as_float(u & 0xFFFF0000u);
            }
        }
        while (nstored < nval) {
            float sc = 1.0f / fmaxf((float)(cur_end - cur_start), 1.0f);
            *(unsigned*)&s_m[wave * 16 + nstored][lane * 2] =
                pack2bf(alo * sc, ahi * sc);
            alo = 0.f; ahi = 0.f;
            ++nstored;
            if (nstored < nval) {
                cur_start = cur_end;
                cur_end   = offs[first + nstored + 1];
            }
        }
    }
    __syncthreads();

    f32x4 acc[4][2];
#pragma unroll
    for (int nt = 0; nt < 4; ++nt) {
        acc[nt][0] = (f32x4){0.f, 0.f, 0.f, 0.f};
        acc[nt][1] = (f32x4){0.f, 0.f, 0.f, 0.f};
    }

#pragma unroll
    for (int ks = 0; ks < 8; ++ks) {
        const int kk = (ks & 3) * 32 + gA * 8;
        const ushort (*S)[136] = (ks < 4) ? s_m : s_v;
        const ushort* wrow = Wt + ks * 32 + gA * 8;
        bf16x8 bf0 = __builtin_bit_cast(bf16x8,
            *(const uint4*)(wrow + (oc0 + rA) * 256));
        bf16x8 bf1 = __builtin_bit_cast(bf16x8,
            *(const uint4*)(wrow + (oc0 + 16 + rA) * 256));
#pragma unroll
        for (int nt = 0; nt < 4; ++nt) {
            bf16x8 af = __builtin_bit_cast(bf16x8,
                *(const uint4*)&S[nt * 16 + rA][kk]);
            acc[nt][0] = __builtin_amdgcn_mfma_f32_16x16x32_bf16(af, bf0, acc[nt][0], 0, 0, 0);
            acc[nt][1] = __builtin_amdgcn_mfma_f32_16x16x32_bf16(af, bf1, acc[nt][1], 0, 0, 0);
        }
    }

#pragma unroll
    for (int nt = 0; nt < 4; ++nt) {
        int nbase = node0 + nt * 16 + gA * 4;
#pragma unroll
        for (int r = 0; r < 4; ++r) {
            int node = nbase + r;
            if (node < n_nodes) {
                out[(size_t)node * CH + oc0 + rA]      = fmaxf(acc[nt][0][r] + b0, 0.f);
                out[(size_t)node * CH + oc0 + 16 + rA] = fmaxf(acc[nt][1][r] + b1, 0.f);
            }
        }
    }
}

// ---------------------------------------------------------------------------
// legacy helpers for fallback tiers
// ---------------------------------------------------------------------------
__global__ __launch_bounds__(256) void hist_kernel(
    const void* __restrict__ edges, int* __restrict__ deg, int n_edges)
{
    const int f = detect_f(edges);
    int e = blockIdx.x * 256 + threadIdx.x;
    if (e >= n_edges) return;
    atomicAdd(&deg[load_dst(edges, e, n_edges, f)], 1);
}

__global__ __launch_bounds__(SC_T) void scan_blocks(
    const int* __restrict__ deg, int* __restrict__ offs,
    int* __restrict__ bsums, int n)
{
    __shared__ int s_sum[SC_T];
    const int t = threadIdx.x;
    const int base = blockIdx.x * SC_T * SC_I + t * SC_I;
    int v[SC_I];
    int tsum = 0;
#pragma unroll
    for (int i = 0; i < SC_I; ++i) {
        int idx = base + i;
        v[i] = (idx < n) ? deg[idx] : 0;
        tsum += v[i];
    }
    s_sum[t] = tsum;
    __syncthreads();
    for (int off = 1; off < SC_T; off <<= 1) {
        int val = (t >= off) ? s_sum[t - off] : 0;
        __syncthreads();
        s_sum[t] += val;
        __syncthreads();
    }
    int run = s_sum[t] - tsum;
#pragma unroll
    for (int i = 0; i < SC_I; ++i) {
        int idx = base + i;
        if (idx < n) offs[idx] = run;
        run += v[i];
    }
    if (t == SC_T - 1) bsums[blockIdx.x] = s_sum[t];
}

__global__ __launch_bounds__(256) void fixup_kernel(
    int* __restrict__ offs, const int* __restrict__ bsums,
    int* __restrict__ cursor, int n)
{
    int i = blockIdx.x * 256 + threadIdx.x;
    if (i >= n) return;
    int bucket = i / (SC_T * SC_I);
    int add = 0;
    for (int j = 0; j < bucket; ++j) add += bsums[j];
    int o = offs[i] + add;
    offs[i] = o;
    cursor[i] = o;
}

__global__ __launch_bounds__(256) void sort_kernel(
    const void* __restrict__ edges,
    int* __restrict__ cursor, int* __restrict__ sorted, int n_edges)
{
    const int f = detect_f(edges);
    int e = blockIdx.x * 256 + threadIdx.x;
    if (e >= n_edges) return;
    int d = load_dst(edges, e, n_edges, f);
    int s = load_src(edges, e, f);
    int pos = atomicAdd(&cursor[d], 1);
    sorted[pos] = s;
}

__global__ __launch_bounds__(256) void fused_kernel(
    const float* __restrict__ x,
    const int* __restrict__ sorted,
    const int* __restrict__ deg,
    const int* __restrict__ offs,
    const float* __restrict__ Wl,
    const float* __restrict__ Wr,
    const float* __restrict__ b,
    float* __restrict__ out,
    int n_nodes)
{
    __shared__ float s_m[CH][LSTR];
    __shared__ float s_v[CH][LSTR];

    const int node0 = blockIdx.x * NB;
    const int tid   = threadIdx.x;
    const int wave  = tid >> 6;
    const int lane  = tid & 63;

    for (int nn = 0; nn < 16; ++nn) {
        int n    = wave * 16 + nn;
        int node = node0 + n;
        float a0 = 0.f, a1 = 0.f, x0 = 0.f, x1 = 0.f;
        if (node < n_nodes) {
            const float* xr = x + (long long)node * CH;
            x0 = xr[lane];
            x1 = xr[lane + 64];
            int base = offs[node];
            int dg   = deg[node];
            for (int j0 = 0; j0 < dg; j0 += 64) {
                int m  = min(64, dg - j0);
                int sv = (j0 + lane < dg) ? sorted[base + j0 + lane] : 0;
                int jj = 0;
                for (; jj + 8 <= m; jj += 8) {
                    float v0[8], v1[8];
#pragma unroll
                    for (int u = 0; u < 8; ++u) {
                        int s = __shfl(sv, jj + u);
                        const float* p = x + (long long)s * CH;
                        v0[u] = p[lane];
                        v1[u] = p[lane + 64];
                    }
#pragma unroll
                    for (int u = 0; u < 8; ++u) { a0 += v0[u]; a1 += v1[u]; }
                }
                for (; jj < m; ++jj) {
                    int s = __shfl(sv, jj);
                    const float* p = x + (long long)s * CH;
                    a0 += p[lane];
                    a1 += p[lane + 64];
                }
            }
            float inv = 1.0f / fmaxf((float)dg, 1.0f);
            a0 *= inv; a1 *= inv;
        }
        s_m[lane][n]      = a0;
        s_m[lane + 64][n] = a1;
        s_v[lane][n]      = x0;
        s_v[lane + 64][n] = x1;
    }
    __syncthreads();

    const int cg = (tid & 31) * 4;
    const int ng = (tid >> 5) * 8;

    float acc[8][4];
#pragma unroll
    for (int u = 0; u < 8; ++u)
#pragma unroll
        for (int j = 0; j < 4; ++j) acc[u][j] = 0.f;

#pragma unroll 4
    for (int k = 0; k < CH; ++k) {
        const float* mr = &s_m[k][ng];
        const float* vr = &s_v[k][ng];
        float4 wl = *(const float4*)(Wl + k * CH + cg);
        float4 wr = *(const float4*)(Wr + k * CH + cg);
#pragma unroll
        for (int u = 0; u < 8; ++u) {
            float m  = mr[u];
            float xv = vr[u];
            acc[u][0] += m * wl.x + xv * wr.x;
            acc[u][1] += m * wl.y + xv * wr.y;
            acc[u][2] += m * wl.z + xv * wr.z;
            acc[u][3] += m * wl.w + xv * wr.w;
        }
    }

    float4 bb = *(const float4*)(b + cg);
#pragma unroll
    for (int u = 0; u < 8; ++u) {
        int node = node0 + ng + u;
        if (node < n_nodes) {
            float4 o;
            o.x = fmaxf(acc[u][0] + bb.x, 0.0f);
            o.y = fmaxf(acc[u][1] + bb.y, 0.0f);
            o.z = fmaxf(acc[u][2] + bb.z, 0.0f);
            o.w = fmaxf(acc[u][3] + bb.w, 0.0f);
            *(float4*)(out + (long long)node * CH + cg) = o;
        }
    }
}

__global__ __launch_bounds__(256) void scatter_kernel(
    const float* __restrict__ x, const void* __restrict__ edges,
    float* __restrict__ agg, float* __restrict__ cnt, int n_edges)
{
    const int f = detect_f(edges);
    int e = blockIdx.x * 4 + (threadIdx.x >> 6);
    if (e >= n_edges) return;
    int lane = threadIdx.x & 63;
    long long s = load_src(edges, e, f);
    long long d = load_dst(edges, e, n_edges, f);
    const float* xs = x + s * (long long)CH;
    float*       ad = agg + d * (long long)CH;
    unsafeAtomicAdd(ad + lane,      xs[lane]);
    unsafeAtomicAdd(ad + lane + 64, xs[lane + 64]);
    if (lane == 0) unsafeAtomicAdd(cnt + d, 1.0f);
}

__global__ __launch_bounds__(256) void sage_out_kernel(
    const float* __restrict__ x, const float* agg, const float* __restrict__ cnt,
    const float* __restrict__ Wl, const float* __restrict__ Wr,
    const float* __restrict__ b, float* out, int n_nodes)
{
    __shared__ float s_mean[FB_NB][CH];
    __shared__ float s_x[FB_NB][CH];
    const int node0 = blockIdx.x * FB_NB;
    const int tid   = threadIdx.x;
    for (int i = tid; i < FB_NB * CH; i += 256) {
        int n = i >> 7, c = i & (CH - 1);
        int node = node0 + n;
        float a = 0.0f, xv = 0.0f, inv = 1.0f;
        if (node < n_nodes) {
            inv = 1.0f / fmaxf(cnt[node], 1.0f);
            a  = agg[(long long)node * CH + c];
            xv = x[(long long)node * CH + c];
        }
        s_mean[n][c] = a * inv;
        s_x[n][c]    = xv;
    }
    __syncthreads();
    const int cg = (tid & 31) * 4, nbase = (tid >> 5) * 2;
    float acc0[4] = {0,0,0,0}, acc1[4] = {0,0,0,0};
#pragma unroll 8
    for (int k = 0; k < CH; ++k) {
        float4 wl = *(const float4*)(Wl + k * CH + cg);
        float4 wr = *(const float4*)(Wr + k * CH + cg);
        float m0 = s_mean[nbase][k],   m1 = s_mean[nbase + 1][k];
        float x0 = s_x[nbase][k],      x1 = s_x[nbase + 1][k];
        acc0[0] += m0*wl.x + x0*wr.x;  acc0[1] += m0*wl.y + x0*wr.y;
        acc0[2] += m0*wl.z + x0*wr.z;  acc0[3] += m0*wl.w + x0*wr.w;
        acc1[0] += m1*wl.x + x1*wr.x;  acc1[1] += m1*wl.y + x1*wr.y;
        acc1[2] += m1*wl.z + x1*wr.z;  acc1[3] += m1*wl.w + x1*wr.w;
    }
    float4 bb = *(const float4*)(b + cg);
    int n0 = node0 + nbase, n1 = n0 + 1;
    if (n0 < n_nodes) {
        float4 o = { fmaxf(acc0[0]+bb.x,0.f), fmaxf(acc0[1]+bb.y,0.f),
                     fmaxf(acc0[2]+bb.z,0.f), fmaxf(acc0[3]+bb.w,0.f) };
        *(float4*)(out + (long long)n0 * CH + cg) = o;
    }
    if (n1 < n_nodes) {
        float4 o = { fmaxf(acc1[0]+bb.x,0.f), fmaxf(acc1[1]+bb.y,0.f),
                     fmaxf(acc1[2]+bb.z,0.f), fmaxf(acc1[3]+bb.w,0.f) };
        *(float4*)(out + (long long)n1 * CH + cg) = o;
    }
}

extern "C" void kernel_launch(void* const* d_in, const int* in_sizes, int n_in,
                              void* d_out, int out_size, void* d_ws, size_t ws_size,
                              hipStream_t stream)
{
    const float* x     = (const float*)d_in[0];
    const void*  edges = d_in[1];
    const float* Wl    = (const float*)d_in[2];
    const float* Wr    = (const float*)d_in[3];
    const float* b     = (const float*)d_in[4];
    float*       out   = (float*)d_out;

    const int n_nodes = in_sizes[0] / CH;
    const int n_edges = in_sizes[1] / 2;
    const long long n_x = (long long)n_nodes * CH;

    char* ws = (char*)d_ws;
    const size_t ints_n = (size_t)n_nodes * sizeof(int);
    const int    nscan  = (n_nodes + SC_T * SC_I - 1) / (SC_T * SC_I);
    const int    nbins  = (n_nodes + CSZ - 1) >> CSH;

    // tier-1 layout: offs(n+1) | btot(512) | cursor0(512) | sorted | xb∪binned | Wt
    const size_t offs_b      = ((size_t)(n_nodes + 1) * sizeof(int) + 255) & ~(size_t)255;
    const size_t btot_off    = offs_b;
    const size_t gcur_off    = btot_off + NBMAX * sizeof(int);
    const size_t sorted_off  = (gcur_off + NBMAX * sizeof(int) + 255) & ~(size_t)255;
    const size_t xb_off      = (sorted_off + (size_t)n_edges * sizeof(int) + 255) & ~(size_t)255;
    const size_t xb_bytes    = ((size_t)n_x * sizeof(ushort) > (size_t)n_edges * 4)
                             ? (size_t)n_x * sizeof(ushort) : (size_t)n_edges * 4;
    const size_t wt_off      = (xb_off + xb_bytes + 255) & ~(size_t)255;
    const size_t t1_need     = wt_off + (size_t)(CH * 2 * CH) * sizeof(ushort);

    // tier-3 layout (f32 path w/ legacy sort)
    const size_t t3_need = 3 * ints_n + 1024 * sizeof(int) + (size_t)n_edges * sizeof(int);

    if (ws_size >= t1_need && nbins <= NBMAX && n_nodes < (1 << 22)) {
        int*      offs    = (int*)ws;
        int*      btot    = (int*)(ws + btot_off);
        int*      cursor0 = (int*)(ws + gcur_off);
        int*      sorted  = (int*)(ws + sorted_off);
        ushort*   xb      = (ushort*)(ws + xb_off);
        unsigned* binned  = (unsigned*)(ws + xb_off);   // aliases xb until sortfine2 done
        ushort*   Wt      = (ushort*)(ws + wt_off);

        // zero btot + cursor0 in one shot (adjacent)
        hipMemsetAsync(btot, 0, 2 * NBMAX * sizeof(int), stream);

        const int hist_blocks = (n_edges + 256 * A1_E - 1) / (256 * A1_E);
        const long long cast_blocks = (n_x + 2047) / 2048;
        const int pb = (int)((cast_blocks > hist_blocks) ? cast_blocks : hist_blocks);
        const int a1b = (n_edges + A1_T * A1_E - 1) / (A1_T * A1_E);

        const size_t binned_off  = (t1_need + 255) & ~(size_t)255;
        const size_t t1b_need    = binned_off + (size_t)n_edges * 4;
        if (ws_size >= t1b_need) {
            // binned has its own region: full fusion (hist+cast+wt in one pass).
            unsigned* binned2 = (unsigned*)(ws + binned_off);
            prep2_kernel<<<pb, 256, 0, stream>>>(edges, btot, n_edges, x, xb, n_x,
                                                 nbins, hist_blocks, Wl, Wr, Wt, 1);
            bin_kernel<<<a1b, A1_T, 0, stream>>>(edges, btot, cursor0, binned2,
                                                 n_edges, nbins);
            sortfine2_kernel<<<nbins, CSZ, 0, stream>>>(binned2, btot, offs, sorted,
                                                        n_nodes, n_edges, nbins);
        } else {
            // binned aliases xb: sort first, cast after.
            prep2_kernel<<<hist_blocks, 256, 0, stream>>>(edges, btot, n_edges,
                                                          x, xb, 0, nbins, hist_blocks,
                                                          Wl, Wr, Wt, 0);
            bin_kernel<<<a1b, A1_T, 0, stream>>>(edges, btot, cursor0, binned,
                                                 n_edges, nbins);
            sortfine2_kernel<<<nbins, CSZ, 0, stream>>>(binned, btot, offs, sorted,
                                                        n_nodes, n_edges, nbins);
            prep2_kernel<<<(int)cast_blocks, 256, 0, stream>>>(edges, btot, n_edges,
                                                               x, xb, n_x, nbins, 0,
                                                               Wl, Wr, Wt, 1);
        }

        const int ntiles = (n_nodes + NB - 1) / NB;
        fused_mfma_kernel<<<ntiles, 256, 0, stream>>>(
            xb, sorted, offs, Wt, b, out, n_nodes, n_edges);
    } else if (ws_size >= t3_need && nscan <= 1024) {
        int* deg    = (int*)ws;
        int* offs   = (int*)(ws + ints_n);
        int* cursor = (int*)(ws + 2 * ints_n);
        int* bsums  = (int*)(ws + 3 * ints_n);
        int* sorted = (int*)(ws + 3 * ints_n + 1024 * sizeof(int));

        hipMemsetAsync(deg, 0, ints_n, stream);
        const int eb = (n_edges + 255) / 256;
        hist_kernel<<<eb, 256, 0, stream>>>(edges, deg, n_edges);
        scan_blocks<<<nscan, SC_T, 0, stream>>>(deg, offs, bsums, n_nodes);
        fixup_kernel<<<(n_nodes + 255) / 256, 256, 0, stream>>>(offs, bsums, cursor, n_nodes);
        sort_kernel<<<eb, 256, 0, stream>>>(edges, cursor, sorted, n_edges);
        fused_kernel<<<(n_nodes + NB - 1) / NB, 256, 0, stream>>>(
            x, sorted, deg, offs, Wl, Wr, b, out, n_nodes);
    } else {
        float* agg = out;
        float* cnt = (float*)ws;
        hipMemsetAsync(agg, 0, (size_t)n_nodes * CH * sizeof(float), stream);
        hipMemsetAsync(cnt, 0, ints_n, stream);
        scatter_kernel<<<(n_edges + 3) / 4, 256, 0, stream>>>(x, edges, agg, cnt, n_edges);
        sage_out_kernel<<<(n_nodes + FB_NB - 1) / FB_NB, 256, 0, stream>>>(x, agg, cnt, Wl, Wr, b, out, n_nodes);
    }
}